// Round 27
// baseline (216.090 us; speedup 1.0000x reference)
//
#include <hip/hip_runtime.h>
#include <math.h>

#define D_MODEL 1024
#define N_HEADS 16
#define D_HEAD  64
#define LSR_RANK 32
#define BATCH 2
#define SEQ 2048
#define M_TOT (BATCH*SEQ)

typedef __attribute__((ext_vector_type(8))) short short8v;
typedef __attribute__((ext_vector_type(4))) short short4v;
typedef __attribute__((ext_vector_type(4))) float f32x4;

static __device__ __forceinline__ ushort bfhi(float f) {
    union { float f; unsigned u; } c; c.f = f;
    return (ushort)(c.u >> 16);
}
static __device__ __forceinline__ float bff(ushort h) {
    union { unsigned u; float f; } c; c.u = ((unsigned)h) << 16;
    return c.f;
}
static __device__ __forceinline__ ushort f2bf_rn(float f) {
    union { float f; unsigned u; } c; c.f = f;
    unsigned r = c.u + 0x7FFF + ((c.u >> 16) & 1);
    return (ushort)(r >> 16);
}
static __device__ __forceinline__ void split8(const float4 a, const float4 b,
                                              short8v& h, short8v& l) {
    ushort h0 = bfhi(a.x), h1 = bfhi(a.y), h2 = bfhi(a.z), h3 = bfhi(a.w);
    ushort h4 = bfhi(b.x), h5 = bfhi(b.y), h6 = bfhi(b.z), h7 = bfhi(b.w);
    h[0] = (short)h0; h[1] = (short)h1; h[2] = (short)h2; h[3] = (short)h3;
    h[4] = (short)h4; h[5] = (short)h5; h[6] = (short)h6; h[7] = (short)h7;
    l[0] = (short)bfhi(a.x - bff(h0)); l[1] = (short)bfhi(a.y - bff(h1));
    l[2] = (short)bfhi(a.z - bff(h2)); l[3] = (short)bfhi(a.w - bff(h3));
    l[4] = (short)bfhi(b.x - bff(h4)); l[5] = (short)bfhi(b.y - bff(h5));
    l[6] = (short)bfhi(b.z - bff(h6)); l[7] = (short)bfhi(b.w - bff(h7));
}
static __device__ __forceinline__ void trunc8(const float4 a, const float4 b,
                                              short8v& h) {
    h[0] = (short)bfhi(a.x); h[1] = (short)bfhi(a.y);
    h[2] = (short)bfhi(a.z); h[3] = (short)bfhi(a.w);
    h[4] = (short)bfhi(b.x); h[5] = (short)bfhi(b.y);
    h[6] = (short)bfhi(b.z); h[7] = (short)bfhi(b.w);
}

// ---------------------------------------------------------------------------
// Weff_tmp[k][z*512+c] = sum_d W[k, h*64+d] * Wlsr[h, d, r]  (z=0:Wq, 1:Wk)
// ---------------------------------------------------------------------------
__global__ __launch_bounds__(256) void eff_weight2(
    const float* __restrict__ Wq, const float* __restrict__ Wq_lsr,
    const float* __restrict__ Wk, const float* __restrict__ Wk_lsr,
    float* __restrict__ Weff_tmp)
{
    const int z = blockIdx.y;
    const float* W    = z ? Wk : Wq;
    const float* Wlsr = z ? Wk_lsr : Wq_lsr;
    const int base = z << 9;
    int idx = blockIdx.x * 256 + threadIdx.x;
    int k = idx >> 9;
    int c = idx & 511;
    int h = c >> 5;
    int r = c & 31;
    const float* wrow = W + (size_t)k * D_MODEL + h * D_HEAD;
    const float* lsr  = Wlsr + (size_t)h * D_HEAD * LSR_RANK + r;
    float acc = 0.f;
    #pragma unroll
    for (int d = 0; d < D_HEAD; ++d)
        acc = fmaf(wrow[d], lsr[d * LSR_RANK], acc);
    Weff_tmp[(size_t)k * 1024 + base + c] = acc;
}

__global__ __launch_bounds__(256) void eff_bias_kernel(
    const float* __restrict__ bq, const float* __restrict__ Wq_lsr,
    const float* __restrict__ bk, const float* __restrict__ Wk_lsr,
    const float* __restrict__ bv, float* __restrict__ bcat)
{
    int c = blockIdx.x * 256 + threadIdx.x;
    if (c < 1024) {
        const float* bias = (c < 512) ? bq : bk;
        const float* lsr  = (c < 512) ? Wq_lsr : Wk_lsr;
        int cc = c & 511;
        int h = cc >> 5, r = cc & 31;
        float acc = 0.f;
        #pragma unroll
        for (int d = 0; d < D_HEAD; ++d)
            acc = fmaf(bias[h * D_HEAD + d],
                       lsr[(size_t)h * D_HEAD * LSR_RANK + d * LSR_RANK + r], acc);
        bcat[c] = acc;
    } else {
        bcat[c] = bv[c - 1024];
    }
}

// ---------------------------------------------------------------------------
// Dual 1024x1024 fp32 transpose: z=0: in0->out0, z=1: in1->out1.
// ---------------------------------------------------------------------------
__global__ __launch_bounds__(256) void transpose2(
    const float* __restrict__ in0, float* __restrict__ out0,
    const float* __restrict__ in1, float* __restrict__ out1)
{
    const float* in  = blockIdx.z ? in1 : in0;
    float* out       = blockIdx.z ? out1 : out0;
    __shared__ float t[64][65];
    const int tid = threadIdx.x;
    const int r0 = blockIdx.y * 64, c0 = blockIdx.x * 64;
    const int tr = tid >> 4, tc = tid & 15;
    #pragma unroll
    for (int i = 0; i < 4; ++i) {
        float4 v = *(const float4*)&in[(size_t)(r0 + tr + i * 16) * 1024 + c0 + tc * 4];
        t[tr + i * 16][tc * 4 + 0] = v.x;
        t[tr + i * 16][tc * 4 + 1] = v.y;
        t[tr + i * 16][tc * 4 + 2] = v.z;
        t[tr + i * 16][tc * 4 + 3] = v.w;
    }
    __syncthreads();
    #pragma unroll
    for (int i = 0; i < 4; ++i) {
        float4 v;
        v.x = t[tc * 4 + 0][tr + i * 16];
        v.y = t[tc * 4 + 1][tr + i * 16];
        v.z = t[tc * 4 + 2][tr + i * 16];
        v.w = t[tc * 4 + 3][tr + i * 16];
        *(float4*)&out[(size_t)(c0 + tr + i * 16) * 1024 + r0 + tc * 4] = v;
    }
}

// ---------------------------------------------------------------------------
// Transpose + bf16-rn: Wo[1024][1024] fp32 -> Wot transposed bf16.
// ---------------------------------------------------------------------------
__global__ __launch_bounds__(256) void tsplit_rn1024(
    const float* __restrict__ in, ushort* __restrict__ out)
{
    __shared__ float t[64][65];
    const int tid = threadIdx.x;
    const int r0 = blockIdx.y * 64, c0 = blockIdx.x * 64;
    const int tr = tid >> 4, tc = tid & 15;
    #pragma unroll
    for (int i = 0; i < 4; ++i) {
        float4 v = *(const float4*)&in[(size_t)(r0 + tr + i * 16) * 1024 + c0 + tc * 4];
        t[tr + i * 16][tc * 4 + 0] = v.x;
        t[tr + i * 16][tc * 4 + 1] = v.y;
        t[tr + i * 16][tc * 4 + 2] = v.z;
        t[tr + i * 16][tc * 4 + 3] = v.w;
    }
    __syncthreads();
    #pragma unroll
    for (int i = 0; i < 4; ++i) {
        short4v hv = {(short)f2bf_rn(t[tc * 4 + 0][tr + i * 16]),
                      (short)f2bf_rn(t[tc * 4 + 1][tr + i * 16]),
                      (short)f2bf_rn(t[tc * 4 + 2][tr + i * 16]),
                      (short)f2bf_rn(t[tc * 4 + 3][tr + i * 16])};
        *(short4v*)&out[(size_t)(c0 + tr + i * 16) * 1024 + r0 + tc * 4] = hv;
    }
}

// ---------------------------------------------------------------------------
// Fused projection GEMM (r22-measured-good) — UNCHANGED.
// ---------------------------------------------------------------------------
__global__ __launch_bounds__(256) void gemm_proj_fused(
    const float* __restrict__ x,
    const float* __restrict__ Wcat_t,
    const float* __restrict__ bcat,
    float* __restrict__ Yqk,
    short* __restrict__ Kth, short* __restrict__ Ktl,
    short* __restrict__ Vbf)
{
    __shared__ __align__(16) short Ah[128 * 40], Al[128 * 40];
    __shared__ __align__(16) short Bh[128 * 40], Bl[128 * 40];

    const int tid = threadIdx.x;
    const int bx = blockIdx.x;
    const int m0 = blockIdx.y * 128, n0 = bx * 128;
    const bool vhalf = (bx >= 8);
    const int wid = tid >> 6, wr = wid >> 1, wc = wid & 1;
    const int lane = tid & 63, fr = lane & 15, fq = lane >> 4;
    const int srow = tid >> 1;
    const int skq  = (tid & 1) << 4;

    f32x4 acc[4][4];
    #pragma unroll
    for (int i = 0; i < 4; ++i)
        #pragma unroll
        for (int j = 0; j < 4; ++j)
            acc[i][j] = (f32x4){0.f, 0.f, 0.f, 0.f};

    const float* Ag = x + (size_t)(m0 + srow) * 1024 + skq;
    const float* Bg = Wcat_t + (size_t)(n0 + srow) * 1024 + skq;
    short* pAh = &Ah[srow * 40 + skq];
    short* pAl = &Al[srow * 40 + skq];
    short* pBh = &Bh[srow * 40 + skq];
    short* pBl = &Bl[srow * 40 + skq];

    for (int k0 = 0; k0 < 1024; k0 += 32) {
        float4 a0 = *(const float4*)(Ag + k0);
        float4 a1 = *(const float4*)(Ag + k0 + 4);
        float4 a2 = *(const float4*)(Ag + k0 + 8);
        float4 a3 = *(const float4*)(Ag + k0 + 12);
        float4 b0 = *(const float4*)(Bg + k0);
        float4 b1 = *(const float4*)(Bg + k0 + 4);
        float4 b2 = *(const float4*)(Bg + k0 + 8);
        float4 b3 = *(const float4*)(Bg + k0 + 12);
        if (vhalf) {
            short8v h;
            trunc8(a0, a1, h); *(short8v*)pAh = h;
            trunc8(a2, a3, h); *(short8v*)(pAh + 8) = h;
            trunc8(b0, b1, h); *(short8v*)pBh = h;
            trunc8(b2, b3, h); *(short8v*)(pBh + 8) = h;
        } else {
            short8v h, l;
            split8(a0, a1, h, l);
            *(short8v*)pAh = h;  *(short8v*)pAl = l;
            split8(a2, a3, h, l);
            *(short8v*)(pAh + 8) = h;  *(short8v*)(pAl + 8) = l;
            split8(b0, b1, h, l);
            *(short8v*)pBh = h;  *(short8v*)pBl = l;
            split8(b2, b3, h, l);
            *(short8v*)(pBh + 8) = h;  *(short8v*)(pBl + 8) = l;
        }
        __syncthreads();

        short8v afh[4], bfh[4];
        #pragma unroll
        for (int fi = 0; fi < 4; ++fi)
            afh[fi] = *(const short8v*)&Ah[(wr * 64 + fi * 16 + fr) * 40 + fq * 8];
        #pragma unroll
        for (int bj = 0; bj < 4; ++bj)
            bfh[bj] = *(const short8v*)&Bh[(wc * 64 + bj * 16 + fr) * 40 + fq * 8];

        if (vhalf) {
            #pragma unroll
            for (int fi = 0; fi < 4; ++fi)
                #pragma unroll
                for (int bj = 0; bj < 4; ++bj)
                    acc[fi][bj] = __builtin_amdgcn_mfma_f32_16x16x32_bf16(
                        afh[fi], bfh[bj], acc[fi][bj], 0, 0, 0);
        } else {
            short8v afl[4], bfl[4];
            #pragma unroll
            for (int fi = 0; fi < 4; ++fi)
                afl[fi] = *(const short8v*)&Al[(wr * 64 + fi * 16 + fr) * 40 + fq * 8];
            #pragma unroll
            for (int bj = 0; bj < 4; ++bj)
                bfl[bj] = *(const short8v*)&Bl[(wc * 64 + bj * 16 + fr) * 40 + fq * 8];
            #pragma unroll
            for (int fi = 0; fi < 4; ++fi) {
                #pragma unroll
                for (int bj = 0; bj < 4; ++bj) {
                    acc[fi][bj] = __builtin_amdgcn_mfma_f32_16x16x32_bf16(
                        afh[fi], bfh[bj], acc[fi][bj], 0, 0, 0);
                    acc[fi][bj] = __builtin_amdgcn_mfma_f32_16x16x32_bf16(
                        afh[fi], bfl[bj], acc[fi][bj], 0, 0, 0);
                    acc[fi][bj] = __builtin_amdgcn_mfma_f32_16x16x32_bf16(
                        afl[fi], bfh[bj], acc[fi][bj], 0, 0, 0);
                }
            }
        }
        __syncthreads();
    }

    const int b = m0 >> 11;
    #pragma unroll
    for (int fi = 0; fi < 4; ++fi) {
        #pragma unroll
        for (int bj = 0; bj < 4; ++bj) {
            const int r = m0 + wr * 64 + fi * 16 + fq * 4;
            const int gcol = n0 + wc * 64 + bj * 16 + fr;
            const float bv_ = bcat[gcol];
            if (bx < 4) {
                #pragma unroll
                for (int j = 0; j < 4; ++j)
                    Yqk[(size_t)(r + j) * 1024 + gcol] = acc[fi][bj][j] + bv_;
            } else if (bx < 8) {
                const int kc = gcol - 512;
                const int h = kc >> 5, rr = kc & 31;
                short* oh = Kth + (((size_t)(b * 16 + h) * 2048) + (r & 2047)) * 32 + rr;
                short* ol = Ktl + (((size_t)(b * 16 + h) * 2048) + (r & 2047)) * 32 + rr;
                #pragma unroll
                for (int j = 0; j < 4; ++j) {
                    const float v = acc[fi][bj][j] + bv_;
                    const ushort vh = bfhi(v);
                    oh[j * 32] = (short)vh;
                    ol[j * 32] = (short)bfhi(v - bff(vh));
                }
            } else {
                const int vc = gcol - 1024;
                const int h = vc >> 6, d = vc & 63;
                short4v o = {(short)f2bf_rn(acc[fi][bj][0] + bv_),
                             (short)f2bf_rn(acc[fi][bj][1] + bv_),
                             (short)f2bf_rn(acc[fi][bj][2] + bv_),
                             (short)f2bf_rn(acc[fi][bj][3] + bv_)};
                *(short4v*)&Vbf[((size_t)(b * 16 + h) * 64 + d) * 2048 + (r & 2047)] = o;
            }
        }
    }
}

// ---------------------------------------------------------------------------
// Out-proj GEMM, 1-term bf16 (r19-validated) — UNCHANGED.
// ---------------------------------------------------------------------------
__global__ __launch_bounds__(256) void gemm_out_bf(
    const ushort* __restrict__ Obf,
    const ushort* __restrict__ Wot,
    const float* __restrict__ bo,
    float* __restrict__ out)
{
    __shared__ __align__(16) short Ah[128 * 40];
    __shared__ __align__(16) short Bh[128 * 40];

    const int tid = threadIdx.x;
    const int m0 = blockIdx.y * 128, n0 = blockIdx.x * 128;
    const int wid = tid >> 6, wr = wid >> 1, wc = wid & 1;
    const int lane = tid & 63, fr = lane & 15, fq = lane >> 4;
    const int srow = tid >> 1;
    const int skq  = (tid & 1) << 4;

    f32x4 acc[4][4];
    #pragma unroll
    for (int i = 0; i < 4; ++i)
        #pragma unroll
        for (int j = 0; j < 4; ++j)
            acc[i][j] = (f32x4){0.f, 0.f, 0.f, 0.f};

    const ushort* AgH = Obf + (size_t)(m0 + srow) * 1024 + skq;
    const ushort* BgH = Wot + (size_t)(n0 + srow) * 1024 + skq;
    short* pAh = &Ah[srow * 40 + skq];
    short* pBh = &Bh[srow * 40 + skq];

    for (int k0 = 0; k0 < 1024; k0 += 32) {
        *(short8v*)pAh       = *(const short8v*)(AgH + k0);
        *(short8v*)(pAh + 8) = *(const short8v*)(AgH + k0 + 8);
        *(short8v*)pBh       = *(const short8v*)(BgH + k0);
        *(short8v*)(pBh + 8) = *(const short8v*)(BgH + k0 + 8);
        __syncthreads();

        short8v afh[4], bfh[4];
        #pragma unroll
        for (int fi = 0; fi < 4; ++fi)
            afh[fi] = *(const short8v*)&Ah[(wr * 64 + fi * 16 + fr) * 40 + fq * 8];
        #pragma unroll
        for (int bj = 0; bj < 4; ++bj)
            bfh[bj] = *(const short8v*)&Bh[(wc * 64 + bj * 16 + fr) * 40 + fq * 8];
        #pragma unroll
        for (int fi = 0; fi < 4; ++fi)
            #pragma unroll
            for (int bj = 0; bj < 4; ++bj)
                acc[fi][bj] = __builtin_amdgcn_mfma_f32_16x16x32_bf16(
                    afh[fi], bfh[bj], acc[fi][bj], 0, 0, 0);
        __syncthreads();
    }

    #pragma unroll
    for (int fi = 0; fi < 4; ++fi) {
        #pragma unroll
        for (int bj = 0; bj < 4; ++bj) {
            const int r = m0 + wr * 64 + fi * 16 + fq * 4;
            const int c = n0 + wc * 64 + bj * 16 + fr;
            const float bv_ = bo[c];
            #pragma unroll
            for (int j = 0; j < 4; ++j)
                out[(size_t)(r + j) * 1024 + c] = acc[fi][bj][j] + bv_;
        }
    }
}

// ---------------------------------------------------------------------------
// MFMA flash attention v11b: QUAD-Q, rescale-axis bug FIXED.
// r26 failure root cause: `acc[tt][r] *= al[r]` scaled the whole d-block-r
// VECTOR (4 rows) by row-r's factor. Correct: element r (row r) of EACH
// d-block vector: acc[tt][d][r] *= al[r]. Everything else identical to r26.
// ---------------------------------------------------------------------------
#define P_LD  68
#define MASKVAL (-1e30f)

__global__ __launch_bounds__(256) void flash_mfma(
    const float* __restrict__ Yqk,
    const short* __restrict__ Kth, const short* __restrict__ Ktl,
    const short* __restrict__ Vbf,
    ushort* __restrict__ Obf)
{
    const float scale = 0.1767766952966369f;  // 1/sqrt(32)
    const int L = blockIdx.x;
    const int bh = L & 31;
    const int t5 = L >> 5;                     // 0..15
    const int qs = 7 - (t5 >> 1);              // LPT: big quads first
    const int half = t5 & 1;
    const int qt0 = 4 * qs;
    const int b = bh >> 4, h = bh & 15;
    const int tid = threadIdx.x;
    const int w = tid >> 6;                    // 0..3
    const int g = w & 1;                       // row-group within half
    const int p = w >> 1;                      // jt parity
    const int lane = tid & 63;
    const int fr = lane & 15, fq = lane >> 4;
    const int rowbase = half * 32 + g * 16;    // local row base in tile

    __shared__ __align__(16) short Pall[4][16 * P_LD];   // 8704 B
    __shared__ __align__(16) char exraw[2 * 64 * 80];    // 10240 B
    short* Pw = &Pall[w][0];

    // Q fragments for 4 tiles (fully unrolled -> static indices)
    short8v aqh[4], aql[4];
    #pragma unroll
    for (int tt = 0; tt < 4; ++tt) {
        const float* qp_ = Yqk + (size_t)(b * SEQ + (qt0 + tt) * 64 + rowbase + fr) * 1024
                           + h * 32 + fq * 8;
        split8(*(const float4*)qp_, *(const float4*)(qp_ + 4), aqh[tt], aql[tt]);
    }

    f32x4 acc[4][4];           // [tile][d-block]
    float m_[4][4], l_[4][4];  // [tile][r]
    #pragma unroll
    for (int tt = 0; tt < 4; ++tt)
        #pragma unroll
        for (int r = 0; r < 4; ++r) {
            acc[tt][r] = (f32x4){0.f, 0.f, 0.f, 0.f};
            m_[tt][r] = MASKVAL; l_[tt][r] = 0.f;
        }

    const short* kb_h = Kth + (size_t)bh * 2048 * 32;
    const short* kb_l = Ktl + (size_t)bh * 2048 * 32;
    const short* vb   = Vbf + (size_t)bh * 64 * 2048;
    const int kidx = fr * 32 + fq * 8;
    const int vrow = fr * 2048 + fq * 8;

    for (int jt = p; jt <= qt0 + 3; jt += 2) {
        // ---- shared load cluster (feeds all active tiles) ----
        const short* kp_h = kb_h + (size_t)jt * 64 * 32;
        const short* kp_l = kb_l + (size_t)jt * 64 * 32;
        short8v kh0 = *(const short8v*)&kp_h[kidx];
        short8v kh1 = *(const short8v*)&kp_h[kidx + 512];
        short8v kh2 = *(const short8v*)&kp_h[kidx + 1024];
        short8v kh3 = *(const short8v*)&kp_h[kidx + 1536];
        short8v kl0 = *(const short8v*)&kp_l[kidx];
        short8v kl1 = *(const short8v*)&kp_l[kidx + 512];
        short8v kl2 = *(const short8v*)&kp_l[kidx + 1024];
        short8v kl3 = *(const short8v*)&kp_l[kidx + 1536];
        const short* vp = vb + vrow + jt * 64;
        short8v v00 = *(const short8v*)&vp[0];
        short8v v01 = *(const short8v*)&vp[32];
        short8v v10 = *(const short8v*)&vp[16 * 2048];
        short8v v11 = *(const short8v*)&vp[16 * 2048 + 32];
        short8v v20 = *(const short8v*)&vp[32 * 2048];
        short8v v21 = *(const short8v*)&vp[32 * 2048 + 32];
        short8v v30 = *(const short8v*)&vp[48 * 2048];
        short8v v31 = *(const short8v*)&vp[48 * 2048 + 32];

        #pragma unroll
        for (int tt = 0; tt < 4; ++tt) {
            const int qt_t = qt0 + tt;
            if (jt <= qt_t) {
                f32x4 s0 = {0,0,0,0}, s1 = {0,0,0,0}, s2 = {0,0,0,0}, s3 = {0,0,0,0};
                s0 = __builtin_amdgcn_mfma_f32_16x16x32_bf16(aqh[tt], kh0, s0, 0, 0, 0);
                s0 = __builtin_amdgcn_mfma_f32_16x16x32_bf16(aqh[tt], kl0, s0, 0, 0, 0);
                s0 = __builtin_amdgcn_mfma_f32_16x16x32_bf16(aql[tt], kh0, s0, 0, 0, 0);
                s1 = __builtin_amdgcn_mfma_f32_16x16x32_bf16(aqh[tt], kh1, s1, 0, 0, 0);
                s1 = __builtin_amdgcn_mfma_f32_16x16x32_bf16(aqh[tt], kl1, s1, 0, 0, 0);
                s1 = __builtin_amdgcn_mfma_f32_16x16x32_bf16(aql[tt], kh1, s1, 0, 0, 0);
                s2 = __builtin_amdgcn_mfma_f32_16x16x32_bf16(aqh[tt], kh2, s2, 0, 0, 0);
                s2 = __builtin_amdgcn_mfma_f32_16x16x32_bf16(aqh[tt], kl2, s2, 0, 0, 0);
                s2 = __builtin_amdgcn_mfma_f32_16x16x32_bf16(aql[tt], kh2, s2, 0, 0, 0);
                s3 = __builtin_amdgcn_mfma_f32_16x16x32_bf16(aqh[tt], kh3, s3, 0, 0, 0);
                s3 = __builtin_amdgcn_mfma_f32_16x16x32_bf16(aqh[tt], kl3, s3, 0, 0, 0);
                s3 = __builtin_amdgcn_mfma_f32_16x16x32_bf16(aql[tt], kh3, s3, 0, 0, 0);

                s0 *= scale; s1 *= scale; s2 *= scale; s3 *= scale;

                if (jt == qt_t) {
                    #pragma unroll
                    for (int r = 0; r < 4; ++r) {
                        const int q_l = rowbase + fq * 4 + r;
                        s0[r] = (fr      <= q_l) ? s0[r] : MASKVAL;
                        s1[r] = (16 + fr <= q_l) ? s1[r] : MASKVAL;
                        s2[r] = (32 + fr <= q_l) ? s2[r] : MASKVAL;
                        s3[r] = (48 + fr <= q_l) ? s3[r] : MASKVAL;
                    }
                }

                float al[4];
                #pragma unroll
                for (int r = 0; r < 4; ++r) {
                    float mt = fmaxf(fmaxf(s0[r], s1[r]), fmaxf(s2[r], s3[r]));
                    mt = fmaxf(mt, __shfl_xor(mt, 1));
                    mt = fmaxf(mt, __shfl_xor(mt, 2));
                    mt = fmaxf(mt, __shfl_xor(mt, 4));
                    mt = fmaxf(mt, __shfl_xor(mt, 8));
                    const float mnew = fmaxf(m_[tt][r], mt);
                    al[r] = __expf(m_[tt][r] - mnew);
                    m_[tt][r] = mnew;
                    s0[r] = __expf(s0[r] - mnew);
                    s1[r] = __expf(s1[r] - mnew);
                    s2[r] = __expf(s2[r] - mnew);
                    s3[r] = __expf(s3[r] - mnew);
                    float ps = s0[r] + s1[r] + s2[r] + s3[r];
                    ps += __shfl_xor(ps, 1);
                    ps += __shfl_xor(ps, 2);
                    ps += __shfl_xor(ps, 4);
                    ps += __shfl_xor(ps, 8);
                    l_[tt][r] = l_[tt][r] * al[r] + ps;
                }

                #pragma unroll
                for (int r = 0; r < 4; ++r) {
                    const int prow = fq * 4 + r;
                    Pw[prow * P_LD +      fr] = (short)f2bf_rn(s0[r]);
                    Pw[prow * P_LD + 16 + fr] = (short)f2bf_rn(s1[r]);
                    Pw[prow * P_LD + 32 + fr] = (short)f2bf_rn(s2[r]);
                    Pw[prow * P_LD + 48 + fr] = (short)f2bf_rn(s3[r]);
                }
                // FIX (r26 bug): rescale element r (the ROW) of EACH d-block
                // vector, not the whole d-block-r vector.
                #pragma unroll
                for (int r = 0; r < 4; ++r) {
                    acc[tt][0][r] *= al[r];
                    acc[tt][1][r] *= al[r];
                    acc[tt][2][r] *= al[r];
                    acc[tt][3][r] *= al[r];
                }
                short8v pa0 = *(const short8v*)&Pw[fr * P_LD + fq * 8];
                short8v pa1 = *(const short8v*)&Pw[fr * P_LD + 32 + fq * 8];

                acc[tt][0] = __builtin_amdgcn_mfma_f32_16x16x32_bf16(pa0, v00, acc[tt][0], 0, 0, 0);
                acc[tt][0] = __builtin_amdgcn_mfma_f32_16x16x32_bf16(pa1, v01, acc[tt][0], 0, 0, 0);
                acc[tt][1] = __builtin_amdgcn_mfma_f32_16x16x32_bf16(pa0, v10, acc[tt][1], 0, 0, 0);
                acc[tt][1] = __builtin_amdgcn_mfma_f32_16x16x32_bf16(pa1, v11, acc[tt][1], 0, 0, 0);
                acc[tt][2] = __builtin_amdgcn_mfma_f32_16x16x32_bf16(pa0, v20, acc[tt][2], 0, 0, 0);
                acc[tt][2] = __builtin_amdgcn_mfma_f32_16x16x32_bf16(pa1, v21, acc[tt][2], 0, 0, 0);
                acc[tt][3] = __builtin_amdgcn_mfma_f32_16x16x32_bf16(pa0, v30, acc[tt][3], 0, 0, 0);
                acc[tt][3] = __builtin_amdgcn_mfma_f32_16x16x32_bf16(pa1, v31, acc[tt][3], 0, 0, 0);
            }
        }
    }

    // ---- epilogue: 4 merge rounds through the shared ex buffer ----
    char* e = exraw + (size_t)(((g << 6) + lane) * 80);
    #pragma unroll
    for (int tt = 0; tt < 4; ++tt) {
        if (p == 1) {
            short8v a01, a23;
            a01[0] = (short)f2bf_rn(acc[tt][0][0]); a01[1] = (short)f2bf_rn(acc[tt][0][1]);
            a01[2] = (short)f2bf_rn(acc[tt][0][2]); a01[3] = (short)f2bf_rn(acc[tt][0][3]);
            a01[4] = (short)f2bf_rn(acc[tt][1][0]); a01[5] = (short)f2bf_rn(acc[tt][1][1]);
            a01[6] = (short)f2bf_rn(acc[tt][1][2]); a01[7] = (short)f2bf_rn(acc[tt][1][3]);
            a23[0] = (short)f2bf_rn(acc[tt][2][0]); a23[1] = (short)f2bf_rn(acc[tt][2][1]);
            a23[2] = (short)f2bf_rn(acc[tt][2][2]); a23[3] = (short)f2bf_rn(acc[tt][2][3]);
            a23[4] = (short)f2bf_rn(acc[tt][3][0]); a23[5] = (short)f2bf_rn(acc[tt][3][1]);
            a23[6] = (short)f2bf_rn(acc[tt][3][2]); a23[7] = (short)f2bf_rn(acc[tt][3][3]);
            *(short8v*)(e)      = a01;
            *(short8v*)(e + 16) = a23;
            *(f32x4*)(e + 32) = (f32x4){m_[tt][0], m_[tt][1], m_[tt][2], m_[tt][3]};
            *(f32x4*)(e + 48) = (f32x4){l_[tt][0], l_[tt][1], l_[tt][2], l_[tt][3]};
        }
        __syncthreads();
        if (p == 0) {
            short8v a01 = *(const short8v*)(e);
            short8v a23 = *(const short8v*)(e + 16);
            f32x4 m1 = *(const f32x4*)(e + 32);
            f32x4 l1 = *(const f32x4*)(e + 48);
            #pragma unroll
            for (int r = 0; r < 4; ++r) {
                const float mm = fmaxf(m_[tt][r], m1[r]);
                const float a0 = __expf(m_[tt][r] - mm);
                const float a1 = __expf(m1[r] - mm);
                const float inv = 1.f / (l_[tt][r] * a0 + l1[r] * a1);
                const float b0 = bff((ushort)a01[r]);
                const float b1 = bff((ushort)a01[4 + r]);
                const float b2 = bff((ushort)a23[r]);
                const float b3 = bff((ushort)a23[4 + r]);
                const int trow = (qt0 + tt) * 64 + rowbase + fq * 4 + r;
                ushort* op = Obf + (size_t)(b * SEQ + trow) * 1024 + h * 64;
                op[     fr] = f2bf_rn((acc[tt][0][r] * a0 + b0 * a1) * inv);
                op[16 + fr] = f2bf_rn((acc[tt][1][r] * a0 + b1 * a1) * inv);
                op[32 + fr] = f2bf_rn((acc[tt][2][r] * a0 + b2 * a1) * inv);
                op[48 + fr] = f2bf_rn((acc[tt][3][r] * a0 + b3 * a1) * inv);
            }
        }
        __syncthreads();
    }
}

// ---------------------------------------------------------------------------
extern "C" void kernel_launch(void* const* d_in, const int* in_sizes, int n_in,
                              void* d_out, int out_size, void* d_ws, size_t ws_size,
                              hipStream_t stream)
{
    const float* x      = (const float*)d_in[0];
    const float* Wq     = (const float*)d_in[1];
    const float* bq     = (const float*)d_in[2];
    const float* Wk     = (const float*)d_in[3];
    const float* bk     = (const float*)d_in[4];
    const float* Wv     = (const float*)d_in[5];
    const float* bv     = (const float*)d_in[6];
    const float* Wo     = (const float*)d_in[7];
    const float* bo     = (const float*)d_in[8];
    const float* Wq_lsr = (const float*)d_in[9];
    const float* Wk_lsr = (const float*)d_in[10];
    float* out = (float*)d_out;

    float* ws     = (float*)d_ws;
    float* Wcat_t = ws;
    float* bcat   = Wcat_t + (size_t)2048 * 1024;
    float* Yqk    = bcat + 2048;
    float* Weff_tmp = Yqk;
    short* Kth    = (short*)(Yqk + (size_t)M_TOT * 1024);
    short* Ktl    = Kth + (size_t)32 * 2048 * 32;
    short* Vbf    = Ktl + (size_t)32 * 2048 * 32;
    ushort* Obf   = (ushort*)(Vbf + (size_t)32 * 64 * 2048);
    ushort* Wot   = (ushort*)Wcat_t;

    eff_weight2<<<dim3(2048, 2), 256, 0, stream>>>(Wq, Wq_lsr, Wk, Wk_lsr, Weff_tmp);
    eff_bias_kernel<<<8, 256, 0, stream>>>(bq, Wq_lsr, bk, Wk_lsr, bv, bcat);

    transpose2<<<dim3(16, 16, 2), 256, 0, stream>>>(
        Weff_tmp, Wcat_t, Wv, Wcat_t + (size_t)1024 * 1024);

    gemm_proj_fused<<<dim3(16, 32), 256, 0, stream>>>(
        x, Wcat_t, bcat, Yqk, Kth, Ktl, Vbf);

    tsplit_rn1024<<<dim3(16, 16), 256, 0, stream>>>(Wo, Wot);

    flash_mfma<<<512, 256, 0, stream>>>(Yqk, Kth, Ktl, Vbf, Obf);

    gemm_out_bf<<<dim3(8, 32), 256, 0, stream>>>(Obf, Wot, bo, out);
}

// Round 28
// 186.671 us; speedup vs baseline: 1.1576x; 1.1576x over previous
//
#include <hip/hip_runtime.h>
#include <math.h>

#define D_MODEL 1024
#define N_HEADS 16
#define D_HEAD  64
#define LSR_RANK 32
#define BATCH 2
#define SEQ 2048
#define M_TOT (BATCH*SEQ)

typedef __attribute__((ext_vector_type(8))) short short8v;
typedef __attribute__((ext_vector_type(4))) short short4v;
typedef __attribute__((ext_vector_type(4))) float f32x4;

static __device__ __forceinline__ ushort bfhi(float f) {
    union { float f; unsigned u; } c; c.f = f;
    return (ushort)(c.u >> 16);
}
static __device__ __forceinline__ float bff(ushort h) {
    union { unsigned u; float f; } c; c.u = ((unsigned)h) << 16;
    return c.f;
}
static __device__ __forceinline__ ushort f2bf_rn(float f) {
    union { float f; unsigned u; } c; c.f = f;
    unsigned r = c.u + 0x7FFF + ((c.u >> 16) & 1);
    return (ushort)(r >> 16);
}
static __device__ __forceinline__ void split8(const float4 a, const float4 b,
                                              short8v& h, short8v& l) {
    ushort h0 = bfhi(a.x), h1 = bfhi(a.y), h2 = bfhi(a.z), h3 = bfhi(a.w);
    ushort h4 = bfhi(b.x), h5 = bfhi(b.y), h6 = bfhi(b.z), h7 = bfhi(b.w);
    h[0] = (short)h0; h[1] = (short)h1; h[2] = (short)h2; h[3] = (short)h3;
    h[4] = (short)h4; h[5] = (short)h5; h[6] = (short)h6; h[7] = (short)h7;
    l[0] = (short)bfhi(a.x - bff(h0)); l[1] = (short)bfhi(a.y - bff(h1));
    l[2] = (short)bfhi(a.z - bff(h2)); l[3] = (short)bfhi(a.w - bff(h3));
    l[4] = (short)bfhi(b.x - bff(h4)); l[5] = (short)bfhi(b.y - bff(h5));
    l[6] = (short)bfhi(b.z - bff(h6)); l[7] = (short)bfhi(b.w - bff(h7));
}
static __device__ __forceinline__ void trunc8(const float4 a, const float4 b,
                                              short8v& h) {
    h[0] = (short)bfhi(a.x); h[1] = (short)bfhi(a.y);
    h[2] = (short)bfhi(a.z); h[3] = (short)bfhi(a.w);
    h[4] = (short)bfhi(b.x); h[5] = (short)bfhi(b.y);
    h[6] = (short)bfhi(b.z); h[7] = (short)bfhi(b.w);
}

// ---------------------------------------------------------------------------
// Weff_tmp[k][z*512+c] = sum_d W[k, h*64+d] * Wlsr[h, d, r]  (z=0:Wq, 1:Wk)
// ---------------------------------------------------------------------------
__global__ __launch_bounds__(256) void eff_weight2(
    const float* __restrict__ Wq, const float* __restrict__ Wq_lsr,
    const float* __restrict__ Wk, const float* __restrict__ Wk_lsr,
    float* __restrict__ Weff_tmp)
{
    const int z = blockIdx.y;
    const float* W    = z ? Wk : Wq;
    const float* Wlsr = z ? Wk_lsr : Wq_lsr;
    const int base = z << 9;
    int idx = blockIdx.x * 256 + threadIdx.x;
    int k = idx >> 9;
    int c = idx & 511;
    int h = c >> 5;
    int r = c & 31;
    const float* wrow = W + (size_t)k * D_MODEL + h * D_HEAD;
    const float* lsr  = Wlsr + (size_t)h * D_HEAD * LSR_RANK + r;
    float acc = 0.f;
    #pragma unroll
    for (int d = 0; d < D_HEAD; ++d)
        acc = fmaf(wrow[d], lsr[d * LSR_RANK], acc);
    Weff_tmp[(size_t)k * 1024 + base + c] = acc;
}

__global__ __launch_bounds__(256) void eff_bias_kernel(
    const float* __restrict__ bq, const float* __restrict__ Wq_lsr,
    const float* __restrict__ bk, const float* __restrict__ Wk_lsr,
    const float* __restrict__ bv, float* __restrict__ bcat)
{
    int c = blockIdx.x * 256 + threadIdx.x;
    if (c < 1024) {
        const float* bias = (c < 512) ? bq : bk;
        const float* lsr  = (c < 512) ? Wq_lsr : Wk_lsr;
        int cc = c & 511;
        int h = cc >> 5, r = cc & 31;
        float acc = 0.f;
        #pragma unroll
        for (int d = 0; d < D_HEAD; ++d)
            acc = fmaf(bias[h * D_HEAD + d],
                       lsr[(size_t)h * D_HEAD * LSR_RANK + d * LSR_RANK + r], acc);
        bcat[c] = acc;
    } else {
        bcat[c] = bv[c - 1024];
    }
}

// ---------------------------------------------------------------------------
// Dual 1024x1024 fp32 transpose: z=0: in0->out0, z=1: in1->out1.
// ---------------------------------------------------------------------------
__global__ __launch_bounds__(256) void transpose2(
    const float* __restrict__ in0, float* __restrict__ out0,
    const float* __restrict__ in1, float* __restrict__ out1)
{
    const float* in  = blockIdx.z ? in1 : in0;
    float* out       = blockIdx.z ? out1 : out0;
    __shared__ float t[64][65];
    const int tid = threadIdx.x;
    const int r0 = blockIdx.y * 64, c0 = blockIdx.x * 64;
    const int tr = tid >> 4, tc = tid & 15;
    #pragma unroll
    for (int i = 0; i < 4; ++i) {
        float4 v = *(const float4*)&in[(size_t)(r0 + tr + i * 16) * 1024 + c0 + tc * 4];
        t[tr + i * 16][tc * 4 + 0] = v.x;
        t[tr + i * 16][tc * 4 + 1] = v.y;
        t[tr + i * 16][tc * 4 + 2] = v.z;
        t[tr + i * 16][tc * 4 + 3] = v.w;
    }
    __syncthreads();
    #pragma unroll
    for (int i = 0; i < 4; ++i) {
        float4 v;
        v.x = t[tc * 4 + 0][tr + i * 16];
        v.y = t[tc * 4 + 1][tr + i * 16];
        v.z = t[tc * 4 + 2][tr + i * 16];
        v.w = t[tc * 4 + 3][tr + i * 16];
        *(float4*)&out[(size_t)(c0 + tr + i * 16) * 1024 + r0 + tc * 4] = v;
    }
}

// ---------------------------------------------------------------------------
// Transpose + bf16-rn: Wo[1024][1024] fp32 -> Wot transposed bf16.
// ---------------------------------------------------------------------------
__global__ __launch_bounds__(256) void tsplit_rn1024(
    const float* __restrict__ in, ushort* __restrict__ out)
{
    __shared__ float t[64][65];
    const int tid = threadIdx.x;
    const int r0 = blockIdx.y * 64, c0 = blockIdx.x * 64;
    const int tr = tid >> 4, tc = tid & 15;
    #pragma unroll
    for (int i = 0; i < 4; ++i) {
        float4 v = *(const float4*)&in[(size_t)(r0 + tr + i * 16) * 1024 + c0 + tc * 4];
        t[tr + i * 16][tc * 4 + 0] = v.x;
        t[tr + i * 16][tc * 4 + 1] = v.y;
        t[tr + i * 16][tc * 4 + 2] = v.z;
        t[tr + i * 16][tc * 4 + 3] = v.w;
    }
    __syncthreads();
    #pragma unroll
    for (int i = 0; i < 4; ++i) {
        short4v hv = {(short)f2bf_rn(t[tc * 4 + 0][tr + i * 16]),
                      (short)f2bf_rn(t[tc * 4 + 1][tr + i * 16]),
                      (short)f2bf_rn(t[tc * 4 + 2][tr + i * 16]),
                      (short)f2bf_rn(t[tc * 4 + 3][tr + i * 16])};
        *(short4v*)&out[(size_t)(c0 + tr + i * 16) * 1024 + r0 + tc * 4] = hv;
    }
}

// ---------------------------------------------------------------------------
// Fused projection GEMM (r22-measured-good) — UNCHANGED.
// ---------------------------------------------------------------------------
__global__ __launch_bounds__(256) void gemm_proj_fused(
    const float* __restrict__ x,
    const float* __restrict__ Wcat_t,
    const float* __restrict__ bcat,
    float* __restrict__ Yqk,
    short* __restrict__ Kth, short* __restrict__ Ktl,
    short* __restrict__ Vbf)
{
    __shared__ __align__(16) short Ah[128 * 40], Al[128 * 40];
    __shared__ __align__(16) short Bh[128 * 40], Bl[128 * 40];

    const int tid = threadIdx.x;
    const int bx = blockIdx.x;
    const int m0 = blockIdx.y * 128, n0 = bx * 128;
    const bool vhalf = (bx >= 8);
    const int wid = tid >> 6, wr = wid >> 1, wc = wid & 1;
    const int lane = tid & 63, fr = lane & 15, fq = lane >> 4;
    const int srow = tid >> 1;
    const int skq  = (tid & 1) << 4;

    f32x4 acc[4][4];
    #pragma unroll
    for (int i = 0; i < 4; ++i)
        #pragma unroll
        for (int j = 0; j < 4; ++j)
            acc[i][j] = (f32x4){0.f, 0.f, 0.f, 0.f};

    const float* Ag = x + (size_t)(m0 + srow) * 1024 + skq;
    const float* Bg = Wcat_t + (size_t)(n0 + srow) * 1024 + skq;
    short* pAh = &Ah[srow * 40 + skq];
    short* pAl = &Al[srow * 40 + skq];
    short* pBh = &Bh[srow * 40 + skq];
    short* pBl = &Bl[srow * 40 + skq];

    for (int k0 = 0; k0 < 1024; k0 += 32) {
        float4 a0 = *(const float4*)(Ag + k0);
        float4 a1 = *(const float4*)(Ag + k0 + 4);
        float4 a2 = *(const float4*)(Ag + k0 + 8);
        float4 a3 = *(const float4*)(Ag + k0 + 12);
        float4 b0 = *(const float4*)(Bg + k0);
        float4 b1 = *(const float4*)(Bg + k0 + 4);
        float4 b2 = *(const float4*)(Bg + k0 + 8);
        float4 b3 = *(const float4*)(Bg + k0 + 12);
        if (vhalf) {
            short8v h;
            trunc8(a0, a1, h); *(short8v*)pAh = h;
            trunc8(a2, a3, h); *(short8v*)(pAh + 8) = h;
            trunc8(b0, b1, h); *(short8v*)pBh = h;
            trunc8(b2, b3, h); *(short8v*)(pBh + 8) = h;
        } else {
            short8v h, l;
            split8(a0, a1, h, l);
            *(short8v*)pAh = h;  *(short8v*)pAl = l;
            split8(a2, a3, h, l);
            *(short8v*)(pAh + 8) = h;  *(short8v*)(pAl + 8) = l;
            split8(b0, b1, h, l);
            *(short8v*)pBh = h;  *(short8v*)pBl = l;
            split8(b2, b3, h, l);
            *(short8v*)(pBh + 8) = h;  *(short8v*)(pBl + 8) = l;
        }
        __syncthreads();

        short8v afh[4], bfh[4];
        #pragma unroll
        for (int fi = 0; fi < 4; ++fi)
            afh[fi] = *(const short8v*)&Ah[(wr * 64 + fi * 16 + fr) * 40 + fq * 8];
        #pragma unroll
        for (int bj = 0; bj < 4; ++bj)
            bfh[bj] = *(const short8v*)&Bh[(wc * 64 + bj * 16 + fr) * 40 + fq * 8];

        if (vhalf) {
            #pragma unroll
            for (int fi = 0; fi < 4; ++fi)
                #pragma unroll
                for (int bj = 0; bj < 4; ++bj)
                    acc[fi][bj] = __builtin_amdgcn_mfma_f32_16x16x32_bf16(
                        afh[fi], bfh[bj], acc[fi][bj], 0, 0, 0);
        } else {
            short8v afl[4], bfl[4];
            #pragma unroll
            for (int fi = 0; fi < 4; ++fi)
                afl[fi] = *(const short8v*)&Al[(wr * 64 + fi * 16 + fr) * 40 + fq * 8];
            #pragma unroll
            for (int bj = 0; bj < 4; ++bj)
                bfl[bj] = *(const short8v*)&Bl[(wc * 64 + bj * 16 + fr) * 40 + fq * 8];
            #pragma unroll
            for (int fi = 0; fi < 4; ++fi) {
                #pragma unroll
                for (int bj = 0; bj < 4; ++bj) {
                    acc[fi][bj] = __builtin_amdgcn_mfma_f32_16x16x32_bf16(
                        afh[fi], bfh[bj], acc[fi][bj], 0, 0, 0);
                    acc[fi][bj] = __builtin_amdgcn_mfma_f32_16x16x32_bf16(
                        afh[fi], bfl[bj], acc[fi][bj], 0, 0, 0);
                    acc[fi][bj] = __builtin_amdgcn_mfma_f32_16x16x32_bf16(
                        afl[fi], bfh[bj], acc[fi][bj], 0, 0, 0);
                }
            }
        }
        __syncthreads();
    }

    const int b = m0 >> 11;
    #pragma unroll
    for (int fi = 0; fi < 4; ++fi) {
        #pragma unroll
        for (int bj = 0; bj < 4; ++bj) {
            const int r = m0 + wr * 64 + fi * 16 + fq * 4;
            const int gcol = n0 + wc * 64 + bj * 16 + fr;
            const float bv_ = bcat[gcol];
            if (bx < 4) {
                #pragma unroll
                for (int j = 0; j < 4; ++j)
                    Yqk[(size_t)(r + j) * 1024 + gcol] = acc[fi][bj][j] + bv_;
            } else if (bx < 8) {
                const int kc = gcol - 512;
                const int h = kc >> 5, rr = kc & 31;
                short* oh = Kth + (((size_t)(b * 16 + h) * 2048) + (r & 2047)) * 32 + rr;
                short* ol = Ktl + (((size_t)(b * 16 + h) * 2048) + (r & 2047)) * 32 + rr;
                #pragma unroll
                for (int j = 0; j < 4; ++j) {
                    const float v = acc[fi][bj][j] + bv_;
                    const ushort vh = bfhi(v);
                    oh[j * 32] = (short)vh;
                    ol[j * 32] = (short)bfhi(v - bff(vh));
                }
            } else {
                const int vc = gcol - 1024;
                const int h = vc >> 6, d = vc & 63;
                short4v o = {(short)f2bf_rn(acc[fi][bj][0] + bv_),
                             (short)f2bf_rn(acc[fi][bj][1] + bv_),
                             (short)f2bf_rn(acc[fi][bj][2] + bv_),
                             (short)f2bf_rn(acc[fi][bj][3] + bv_)};
                *(short4v*)&Vbf[((size_t)(b * 16 + h) * 64 + d) * 2048 + (r & 2047)] = o;
            }
        }
    }
}

// ---------------------------------------------------------------------------
// Out-proj GEMM, 1-term bf16 (r19-validated) — UNCHANGED.
// ---------------------------------------------------------------------------
__global__ __launch_bounds__(256) void gemm_out_bf(
    const ushort* __restrict__ Obf,
    const ushort* __restrict__ Wot,
    const float* __restrict__ bo,
    float* __restrict__ out)
{
    __shared__ __align__(16) short Ah[128 * 40];
    __shared__ __align__(16) short Bh[128 * 40];

    const int tid = threadIdx.x;
    const int m0 = blockIdx.y * 128, n0 = blockIdx.x * 128;
    const int wid = tid >> 6, wr = wid >> 1, wc = wid & 1;
    const int lane = tid & 63, fr = lane & 15, fq = lane >> 4;
    const int srow = tid >> 1;
    const int skq  = (tid & 1) << 4;

    f32x4 acc[4][4];
    #pragma unroll
    for (int i = 0; i < 4; ++i)
        #pragma unroll
        for (int j = 0; j < 4; ++j)
            acc[i][j] = (f32x4){0.f, 0.f, 0.f, 0.f};

    const ushort* AgH = Obf + (size_t)(m0 + srow) * 1024 + skq;
    const ushort* BgH = Wot + (size_t)(n0 + srow) * 1024 + skq;
    short* pAh = &Ah[srow * 40 + skq];
    short* pBh = &Bh[srow * 40 + skq];

    for (int k0 = 0; k0 < 1024; k0 += 32) {
        *(short8v*)pAh       = *(const short8v*)(AgH + k0);
        *(short8v*)(pAh + 8) = *(const short8v*)(AgH + k0 + 8);
        *(short8v*)pBh       = *(const short8v*)(BgH + k0);
        *(short8v*)(pBh + 8) = *(const short8v*)(BgH + k0 + 8);
        __syncthreads();

        short8v afh[4], bfh[4];
        #pragma unroll
        for (int fi = 0; fi < 4; ++fi)
            afh[fi] = *(const short8v*)&Ah[(wr * 64 + fi * 16 + fr) * 40 + fq * 8];
        #pragma unroll
        for (int bj = 0; bj < 4; ++bj)
            bfh[bj] = *(const short8v*)&Bh[(wc * 64 + bj * 16 + fr) * 40 + fq * 8];
        #pragma unroll
        for (int fi = 0; fi < 4; ++fi)
            #pragma unroll
            for (int bj = 0; bj < 4; ++bj)
                acc[fi][bj] = __builtin_amdgcn_mfma_f32_16x16x32_bf16(
                    afh[fi], bfh[bj], acc[fi][bj], 0, 0, 0);
        __syncthreads();
    }

    #pragma unroll
    for (int fi = 0; fi < 4; ++fi) {
        #pragma unroll
        for (int bj = 0; bj < 4; ++bj) {
            const int r = m0 + wr * 64 + fi * 16 + fq * 4;
            const int c = n0 + wc * 64 + bj * 16 + fr;
            const float bv_ = bo[c];
            #pragma unroll
            for (int j = 0; j < 4; ++j)
                out[(size_t)(r + j) * 1024 + c] = acc[fi][bj][j] + bv_;
        }
    }
}

// ---------------------------------------------------------------------------
// MFMA flash attention v10 (r25-measured BEST: flash 74.3 us, total 186.8).
// REVERT from quad-Q (r27: 104 us — amortization gain was cancelled by TLP
// loss at 8 waves/CU vs dual's 16). Dual-Q is the measured optimum of the
// amortization x occupancy tradeoff. Byte-exact r25 kernel.
// ---------------------------------------------------------------------------
#define P_LD  68
#define MASKVAL (-1e30f)

__global__ __launch_bounds__(512) void flash_mfma(
    const float* __restrict__ Yqk,
    const short* __restrict__ Kth, const short* __restrict__ Ktl,
    const short* __restrict__ Vbf,
    ushort* __restrict__ Obf)
{
    const float scale = 0.1767766952966369f;  // 1/sqrt(32)
    const int L = blockIdx.x;
    const int bh = L & 31;
    const int qp = 15 - (L >> 5);              // LPT: big pairs first
    const int qtA = 2 * qp, qtB = 2 * qp + 1;
    const int b = bh >> 4, h = bh & 15;
    const int tid = threadIdx.x;
    const int w = tid >> 6;
    const int g = w & 3;
    const int p = w >> 2;
    const int lane = tid & 63;
    const int fr = lane & 15, fq = lane >> 4;

    __shared__ __align__(16) short Pall[8][16 * P_LD];        // 17408 B
    __shared__ __align__(16) char exraw[4 * 64 * 80];         // 20480 B
    short* Pw = &Pall[w][0];

    short8v aqhA, aqlA, aqhB, aqlB;
    {
        const float* qpA = Yqk + (size_t)(b * SEQ + qtA * 64 + g * 16 + fr) * 1024
                           + h * 32 + fq * 8;
        split8(*(const float4*)qpA, *(const float4*)(qpA + 4), aqhA, aqlA);
        const float* qpB = Yqk + (size_t)(b * SEQ + qtB * 64 + g * 16 + fr) * 1024
                           + h * 32 + fq * 8;
        split8(*(const float4*)qpB, *(const float4*)(qpB + 4), aqhB, aqlB);
    }

    f32x4 accA0 = {0,0,0,0}, accA1 = {0,0,0,0}, accA2 = {0,0,0,0}, accA3 = {0,0,0,0};
    f32x4 accB0 = {0,0,0,0}, accB1 = {0,0,0,0}, accB2 = {0,0,0,0}, accB3 = {0,0,0,0};
    float mA[4], lA[4], mB[4], lB[4];
    #pragma unroll
    for (int r = 0; r < 4; ++r) {
        mA[r] = MASKVAL; lA[r] = 0.f;
        mB[r] = MASKVAL; lB[r] = 0.f;
    }

    const short* kb_h = Kth + (size_t)bh * 2048 * 32;
    const short* kb_l = Ktl + (size_t)bh * 2048 * 32;
    const short* vb   = Vbf + (size_t)bh * 64 * 2048;
    const int kidx = fr * 32 + fq * 8;
    const int vrow = fr * 2048 + fq * 8;

    for (int jt = p; jt <= qtB; jt += 2) {
        // ---- shared load cluster (feeds BOTH tiles) ----
        const short* kp_h = kb_h + (size_t)jt * 64 * 32;
        const short* kp_l = kb_l + (size_t)jt * 64 * 32;
        short8v kh0 = *(const short8v*)&kp_h[kidx];
        short8v kh1 = *(const short8v*)&kp_h[kidx + 512];
        short8v kh2 = *(const short8v*)&kp_h[kidx + 1024];
        short8v kh3 = *(const short8v*)&kp_h[kidx + 1536];
        short8v kl0 = *(const short8v*)&kp_l[kidx];
        short8v kl1 = *(const short8v*)&kp_l[kidx + 512];
        short8v kl2 = *(const short8v*)&kp_l[kidx + 1024];
        short8v kl3 = *(const short8v*)&kp_l[kidx + 1536];
        const short* vp = vb + vrow + jt * 64;
        short8v v00 = *(const short8v*)&vp[0];
        short8v v01 = *(const short8v*)&vp[32];
        short8v v10 = *(const short8v*)&vp[16 * 2048];
        short8v v11 = *(const short8v*)&vp[16 * 2048 + 32];
        short8v v20 = *(const short8v*)&vp[32 * 2048];
        short8v v21 = *(const short8v*)&vp[32 * 2048 + 32];
        short8v v30 = *(const short8v*)&vp[48 * 2048];
        short8v v31 = *(const short8v*)&vp[48 * 2048 + 32];

        // ================= tile A (skip wave-uniformly if past causal) ====
        if (jt <= qtA) {
            f32x4 s0 = {0,0,0,0}, s1 = {0,0,0,0}, s2 = {0,0,0,0}, s3 = {0,0,0,0};
            s0 = __builtin_amdgcn_mfma_f32_16x16x32_bf16(aqhA, kh0, s0, 0, 0, 0);
            s0 = __builtin_amdgcn_mfma_f32_16x16x32_bf16(aqhA, kl0, s0, 0, 0, 0);
            s0 = __builtin_amdgcn_mfma_f32_16x16x32_bf16(aqlA, kh0, s0, 0, 0, 0);
            s1 = __builtin_amdgcn_mfma_f32_16x16x32_bf16(aqhA, kh1, s1, 0, 0, 0);
            s1 = __builtin_amdgcn_mfma_f32_16x16x32_bf16(aqhA, kl1, s1, 0, 0, 0);
            s1 = __builtin_amdgcn_mfma_f32_16x16x32_bf16(aqlA, kh1, s1, 0, 0, 0);
            s2 = __builtin_amdgcn_mfma_f32_16x16x32_bf16(aqhA, kh2, s2, 0, 0, 0);
            s2 = __builtin_amdgcn_mfma_f32_16x16x32_bf16(aqhA, kl2, s2, 0, 0, 0);
            s2 = __builtin_amdgcn_mfma_f32_16x16x32_bf16(aqlA, kh2, s2, 0, 0, 0);
            s3 = __builtin_amdgcn_mfma_f32_16x16x32_bf16(aqhA, kh3, s3, 0, 0, 0);
            s3 = __builtin_amdgcn_mfma_f32_16x16x32_bf16(aqhA, kl3, s3, 0, 0, 0);
            s3 = __builtin_amdgcn_mfma_f32_16x16x32_bf16(aqlA, kh3, s3, 0, 0, 0);

            s0 *= scale; s1 *= scale; s2 *= scale; s3 *= scale;

            if (jt == qtA) {
                #pragma unroll
                for (int r = 0; r < 4; ++r) {
                    const int q_l = g * 16 + fq * 4 + r;
                    s0[r] = (fr      <= q_l) ? s0[r] : MASKVAL;
                    s1[r] = (16 + fr <= q_l) ? s1[r] : MASKVAL;
                    s2[r] = (32 + fr <= q_l) ? s2[r] : MASKVAL;
                    s3[r] = (48 + fr <= q_l) ? s3[r] : MASKVAL;
                }
            }

            float al[4];
            #pragma unroll
            for (int r = 0; r < 4; ++r) {
                float mt = fmaxf(fmaxf(s0[r], s1[r]), fmaxf(s2[r], s3[r]));
                mt = fmaxf(mt, __shfl_xor(mt, 1));
                mt = fmaxf(mt, __shfl_xor(mt, 2));
                mt = fmaxf(mt, __shfl_xor(mt, 4));
                mt = fmaxf(mt, __shfl_xor(mt, 8));
                const float mnew = fmaxf(mA[r], mt);
                al[r] = __expf(mA[r] - mnew);
                mA[r] = mnew;
                s0[r] = __expf(s0[r] - mnew);
                s1[r] = __expf(s1[r] - mnew);
                s2[r] = __expf(s2[r] - mnew);
                s3[r] = __expf(s3[r] - mnew);
                float ps = s0[r] + s1[r] + s2[r] + s3[r];
                ps += __shfl_xor(ps, 1);
                ps += __shfl_xor(ps, 2);
                ps += __shfl_xor(ps, 4);
                ps += __shfl_xor(ps, 8);
                lA[r] = lA[r] * al[r] + ps;
            }

            #pragma unroll
            for (int r = 0; r < 4; ++r) {
                const int prow = fq * 4 + r;
                Pw[prow * P_LD +      fr] = (short)f2bf_rn(s0[r]);
                Pw[prow * P_LD + 16 + fr] = (short)f2bf_rn(s1[r]);
                Pw[prow * P_LD + 32 + fr] = (short)f2bf_rn(s2[r]);
                Pw[prow * P_LD + 48 + fr] = (short)f2bf_rn(s3[r]);
            }
            #pragma unroll
            for (int r = 0; r < 4; ++r) {
                accA0[r] *= al[r]; accA1[r] *= al[r];
                accA2[r] *= al[r]; accA3[r] *= al[r];
            }
            short8v pa0 = *(const short8v*)&Pw[fr * P_LD + fq * 8];
            short8v pa1 = *(const short8v*)&Pw[fr * P_LD + 32 + fq * 8];

            accA0 = __builtin_amdgcn_mfma_f32_16x16x32_bf16(pa0, v00, accA0, 0, 0, 0);
            accA0 = __builtin_amdgcn_mfma_f32_16x16x32_bf16(pa1, v01, accA0, 0, 0, 0);
            accA1 = __builtin_amdgcn_mfma_f32_16x16x32_bf16(pa0, v10, accA1, 0, 0, 0);
            accA1 = __builtin_amdgcn_mfma_f32_16x16x32_bf16(pa1, v11, accA1, 0, 0, 0);
            accA2 = __builtin_amdgcn_mfma_f32_16x16x32_bf16(pa0, v20, accA2, 0, 0, 0);
            accA2 = __builtin_amdgcn_mfma_f32_16x16x32_bf16(pa1, v21, accA2, 0, 0, 0);
            accA3 = __builtin_amdgcn_mfma_f32_16x16x32_bf16(pa0, v30, accA3, 0, 0, 0);
            accA3 = __builtin_amdgcn_mfma_f32_16x16x32_bf16(pa1, v31, accA3, 0, 0, 0);
        }

        // ================= tile B (always active: jt <= qtB by loop) ======
        {
            f32x4 s0 = {0,0,0,0}, s1 = {0,0,0,0}, s2 = {0,0,0,0}, s3 = {0,0,0,0};
            s0 = __builtin_amdgcn_mfma_f32_16x16x32_bf16(aqhB, kh0, s0, 0, 0, 0);
            s0 = __builtin_amdgcn_mfma_f32_16x16x32_bf16(aqhB, kl0, s0, 0, 0, 0);
            s0 = __builtin_amdgcn_mfma_f32_16x16x32_bf16(aqlB, kh0, s0, 0, 0, 0);
            s1 = __builtin_amdgcn_mfma_f32_16x16x32_bf16(aqhB, kh1, s1, 0, 0, 0);
            s1 = __builtin_amdgcn_mfma_f32_16x16x32_bf16(aqhB, kl1, s1, 0, 0, 0);
            s1 = __builtin_amdgcn_mfma_f32_16x16x32_bf16(aqlB, kh1, s1, 0, 0, 0);
            s2 = __builtin_amdgcn_mfma_f32_16x16x32_bf16(aqhB, kh2, s2, 0, 0, 0);
            s2 = __builtin_amdgcn_mfma_f32_16x16x32_bf16(aqhB, kl2, s2, 0, 0, 0);
            s2 = __builtin_amdgcn_mfma_f32_16x16x32_bf16(aqlB, kh2, s2, 0, 0, 0);
            s3 = __builtin_amdgcn_mfma_f32_16x16x32_bf16(aqhB, kh3, s3, 0, 0, 0);
            s3 = __builtin_amdgcn_mfma_f32_16x16x32_bf16(aqhB, kl3, s3, 0, 0, 0);
            s3 = __builtin_amdgcn_mfma_f32_16x16x32_bf16(aqlB, kl3, s3, 0, 0, 0);
            s3 = __builtin_amdgcn_mfma_f32_16x16x32_bf16(aqlB, kh3, s3, 0, 0, 0);

            s0 *= scale; s1 *= scale; s2 *= scale; s3 *= scale;

            if (jt == qtB) {
                #pragma unroll
                for (int r = 0; r < 4; ++r) {
                    const int q_l = g * 16 + fq * 4 + r;
                    s0[r] = (fr      <= q_l) ? s0[r] : MASKVAL;
                    s1[r] = (16 + fr <= q_l) ? s1[r] : MASKVAL;
                    s2[r] = (32 + fr <= q_l) ? s2[r] : MASKVAL;
                    s3[r] = (48 + fr <= q_l) ? s3[r] : MASKVAL;
                }
            }

            float al[4];
            #pragma unroll
            for (int r = 0; r < 4; ++r) {
                float mt = fmaxf(fmaxf(s0[r], s1[r]), fmaxf(s2[r], s3[r]));
                mt = fmaxf(mt, __shfl_xor(mt, 1));
                mt = fmaxf(mt, __shfl_xor(mt, 2));
                mt = fmaxf(mt, __shfl_xor(mt, 4));
                mt = fmaxf(mt, __shfl_xor(mt, 8));
                const float mnew = fmaxf(mB[r], mt);
                al[r] = __expf(mB[r] - mnew);
                mB[r] = mnew;
                s0[r] = __expf(s0[r] - mnew);
                s1[r] = __expf(s1[r] - mnew);
                s2[r] = __expf(s2[r] - mnew);
                s3[r] = __expf(s3[r] - mnew);
                float ps = s0[r] + s1[r] + s2[r] + s3[r];
                ps += __shfl_xor(ps, 1);
                ps += __shfl_xor(ps, 2);
                ps += __shfl_xor(ps, 4);
                ps += __shfl_xor(ps, 8);
                lB[r] = lB[r] * al[r] + ps;
            }

            #pragma unroll
            for (int r = 0; r < 4; ++r) {
                const int prow = fq * 4 + r;
                Pw[prow * P_LD +      fr] = (short)f2bf_rn(s0[r]);
                Pw[prow * P_LD + 16 + fr] = (short)f2bf_rn(s1[r]);
                Pw[prow * P_LD + 32 + fr] = (short)f2bf_rn(s2[r]);
                Pw[prow * P_LD + 48 + fr] = (short)f2bf_rn(s3[r]);
            }
            #pragma unroll
            for (int r = 0; r < 4; ++r) {
                accB0[r] *= al[r]; accB1[r] *= al[r];
                accB2[r] *= al[r]; accB3[r] *= al[r];
            }
            short8v pa0 = *(const short8v*)&Pw[fr * P_LD + fq * 8];
            short8v pa1 = *(const short8v*)&Pw[fr * P_LD + 32 + fq * 8];

            accB0 = __builtin_amdgcn_mfma_f32_16x16x32_bf16(pa0, v00, accB0, 0, 0, 0);
            accB0 = __builtin_amdgcn_mfma_f32_16x16x32_bf16(pa1, v01, accB0, 0, 0, 0);
            accB1 = __builtin_amdgcn_mfma_f32_16x16x32_bf16(pa0, v10, accB1, 0, 0, 0);
            accB1 = __builtin_amdgcn_mfma_f32_16x16x32_bf16(pa1, v11, accB1, 0, 0, 0);
            accB2 = __builtin_amdgcn_mfma_f32_16x16x32_bf16(pa0, v20, accB2, 0, 0, 0);
            accB2 = __builtin_amdgcn_mfma_f32_16x16x32_bf16(pa1, v21, accB2, 0, 0, 0);
            accB3 = __builtin_amdgcn_mfma_f32_16x16x32_bf16(pa0, v30, accB3, 0, 0, 0);
            accB3 = __builtin_amdgcn_mfma_f32_16x16x32_bf16(pa1, v31, accB3, 0, 0, 0);
        }
    }

    // ---- epilogue: two merge rounds through the shared ex buffer ----
    char* e = exraw + (size_t)(((g << 6) + lane) * 80);

    // round 1: tile A
    if (p == 1) {
        short8v a01, a23;
        a01[0] = (short)f2bf_rn(accA0[0]); a01[1] = (short)f2bf_rn(accA0[1]);
        a01[2] = (short)f2bf_rn(accA0[2]); a01[3] = (short)f2bf_rn(accA0[3]);
        a01[4] = (short)f2bf_rn(accA1[0]); a01[5] = (short)f2bf_rn(accA1[1]);
        a01[6] = (short)f2bf_rn(accA1[2]); a01[7] = (short)f2bf_rn(accA1[3]);
        a23[0] = (short)f2bf_rn(accA2[0]); a23[1] = (short)f2bf_rn(accA2[1]);
        a23[2] = (short)f2bf_rn(accA2[2]); a23[3] = (short)f2bf_rn(accA2[3]);
        a23[4] = (short)f2bf_rn(accA3[0]); a23[5] = (short)f2bf_rn(accA3[1]);
        a23[6] = (short)f2bf_rn(accA3[2]); a23[7] = (short)f2bf_rn(accA3[3]);
        *(short8v*)(e)      = a01;
        *(short8v*)(e + 16) = a23;
        *(f32x4*)(e + 32) = (f32x4){mA[0], mA[1], mA[2], mA[3]};
        *(f32x4*)(e + 48) = (f32x4){lA[0], lA[1], lA[2], lA[3]};
    }
    __syncthreads();
    if (p == 0) {
        short8v a01 = *(const short8v*)(e);
        short8v a23 = *(const short8v*)(e + 16);
        f32x4 m1 = *(const f32x4*)(e + 32);
        f32x4 l1 = *(const f32x4*)(e + 48);
        #pragma unroll
        for (int r = 0; r < 4; ++r) {
            const float mm = fmaxf(mA[r], m1[r]);
            const float a0 = __expf(mA[r] - mm);
            const float a1 = __expf(m1[r] - mm);
            const float inv = 1.f / (lA[r] * a0 + l1[r] * a1);
            const float b0 = bff((ushort)a01[r]);
            const float b1 = bff((ushort)a01[4 + r]);
            const float b2 = bff((ushort)a23[r]);
            const float b3 = bff((ushort)a23[4 + r]);
            const int trow = qtA * 64 + g * 16 + fq * 4 + r;
            ushort* op = Obf + (size_t)(b * SEQ + trow) * 1024 + h * 64;
            op[     fr] = f2bf_rn((accA0[r] * a0 + b0 * a1) * inv);
            op[16 + fr] = f2bf_rn((accA1[r] * a0 + b1 * a1) * inv);
            op[32 + fr] = f2bf_rn((accA2[r] * a0 + b2 * a1) * inv);
            op[48 + fr] = f2bf_rn((accA3[r] * a0 + b3 * a1) * inv);
        }
    }
    __syncthreads();

    // round 2: tile B
    if (p == 1) {
        short8v a01, a23;
        a01[0] = (short)f2bf_rn(accB0[0]); a01[1] = (short)f2bf_rn(accB0[1]);
        a01[2] = (short)f2bf_rn(accB0[2]); a01[3] = (short)f2bf_rn(accB0[3]);
        a01[4] = (short)f2bf_rn(accB1[0]); a01[5] = (short)f2bf_rn(accB1[1]);
        a01[6] = (short)f2bf_rn(accB1[2]); a01[7] = (short)f2bf_rn(accB1[3]);
        a23[0] = (short)f2bf_rn(accB2[0]); a23[1] = (short)f2bf_rn(accB2[1]);
        a23[2] = (short)f2bf_rn(accB2[2]); a23[3] = (short)f2bf_rn(accB2[3]);
        a23[4] = (short)f2bf_rn(accB3[0]); a23[5] = (short)f2bf_rn(accB3[1]);
        a23[6] = (short)f2bf_rn(accB3[2]); a23[7] = (short)f2bf_rn(accB3[3]);
        *(short8v*)(e)      = a01;
        *(short8v*)(e + 16) = a23;
        *(f32x4*)(e + 32) = (f32x4){mB[0], mB[1], mB[2], mB[3]};
        *(f32x4*)(e + 48) = (f32x4){lB[0], lB[1], lB[2], lB[3]};
    }
    __syncthreads();
    if (p == 0) {
        short8v a01 = *(const short8v*)(e);
        short8v a23 = *(const short8v*)(e + 16);
        f32x4 m1 = *(const f32x4*)(e + 32);
        f32x4 l1 = *(const f32x4*)(e + 48);
        #pragma unroll
        for (int r = 0; r < 4; ++r) {
            const float mm = fmaxf(mB[r], m1[r]);
            const float a0 = __expf(mB[r] - mm);
            const float a1 = __expf(m1[r] - mm);
            const float inv = 1.f / (lB[r] * a0 + l1[r] * a1);
            const float b0 = bff((ushort)a01[r]);
            const float b1 = bff((ushort)a01[4 + r]);
            const float b2 = bff((ushort)a23[r]);
            const float b3 = bff((ushort)a23[4 + r]);
            const int trow = qtB * 64 + g * 16 + fq * 4 + r;
            ushort* op = Obf + (size_t)(b * SEQ + trow) * 1024 + h * 64;
            op[     fr] = f2bf_rn((accB0[r] * a0 + b0 * a1) * inv);
            op[16 + fr] = f2bf_rn((accB1[r] * a0 + b1 * a1) * inv);
            op[32 + fr] = f2bf_rn((accB2[r] * a0 + b2 * a1) * inv);
            op[48 + fr] = f2bf_rn((accB3[r] * a0 + b3 * a1) * inv);
        }
    }
}

// ---------------------------------------------------------------------------
extern "C" void kernel_launch(void* const* d_in, const int* in_sizes, int n_in,
                              void* d_out, int out_size, void* d_ws, size_t ws_size,
                              hipStream_t stream)
{
    const float* x      = (const float*)d_in[0];
    const float* Wq     = (const float*)d_in[1];
    const float* bq     = (const float*)d_in[2];
    const float* Wk     = (const float*)d_in[3];
    const float* bk     = (const float*)d_in[4];
    const float* Wv     = (const float*)d_in[5];
    const float* bv     = (const float*)d_in[6];
    const float* Wo     = (const float*)d_in[7];
    const float* bo     = (const float*)d_in[8];
    const float* Wq_lsr = (const float*)d_in[9];
    const float* Wk_lsr = (const float*)d_in[10];
    float* out = (float*)d_out;

    float* ws     = (float*)d_ws;
    float* Wcat_t = ws;
    float* bcat   = Wcat_t + (size_t)2048 * 1024;
    float* Yqk    = bcat + 2048;
    float* Weff_tmp = Yqk;
    short* Kth    = (short*)(Yqk + (size_t)M_TOT * 1024);
    short* Ktl    = Kth + (size_t)32 * 2048 * 32;
    short* Vbf    = Ktl + (size_t)32 * 2048 * 32;
    ushort* Obf   = (ushort*)(Vbf + (size_t)32 * 64 * 2048);
    ushort* Wot   = (ushort*)Wcat_t;

    eff_weight2<<<dim3(2048, 2), 256, 0, stream>>>(Wq, Wq_lsr, Wk, Wk_lsr, Weff_tmp);
    eff_bias_kernel<<<8, 256, 0, stream>>>(bq, Wq_lsr, bk, Wk_lsr, bv, bcat);

    transpose2<<<dim3(16, 16, 2), 256, 0, stream>>>(
        Weff_tmp, Wcat_t, Wv, Wcat_t + (size_t)1024 * 1024);

    gemm_proj_fused<<<dim3(16, 32), 256, 0, stream>>>(
        x, Wcat_t, bcat, Yqk, Kth, Ktl, Vbf);

    tsplit_rn1024<<<dim3(16, 16), 256, 0, stream>>>(Wo, Wot);

    flash_mfma<<<512, 512, 0, stream>>>(Yqk, Kth, Ktl, Vbf, Obf);

    gemm_out_bf<<<dim3(8, 32), 256, 0, stream>>>(Obf, Wot, bo, out);
}

// Round 29
// 186.504 us; speedup vs baseline: 1.1586x; 1.0009x over previous
//
#include <hip/hip_runtime.h>
#include <math.h>

#define D_MODEL 1024
#define N_HEADS 16
#define D_HEAD  64
#define LSR_RANK 32
#define BATCH 2
#define SEQ 2048
#define M_TOT (BATCH*SEQ)

typedef __attribute__((ext_vector_type(8))) short short8v;
typedef __attribute__((ext_vector_type(4))) short short4v;
typedef __attribute__((ext_vector_type(4))) float f32x4;

static __device__ __forceinline__ ushort bfhi(float f) {
    union { float f; unsigned u; } c; c.f = f;
    return (ushort)(c.u >> 16);
}
static __device__ __forceinline__ float bff(ushort h) {
    union { unsigned u; float f; } c; c.u = ((unsigned)h) << 16;
    return c.f;
}
static __device__ __forceinline__ ushort f2bf_rn(float f) {
    union { float f; unsigned u; } c; c.f = f;
    unsigned r = c.u + 0x7FFF + ((c.u >> 16) & 1);
    return (ushort)(r >> 16);
}
static __device__ __forceinline__ void split8(const float4 a, const float4 b,
                                              short8v& h, short8v& l) {
    ushort h0 = bfhi(a.x), h1 = bfhi(a.y), h2 = bfhi(a.z), h3 = bfhi(a.w);
    ushort h4 = bfhi(b.x), h5 = bfhi(b.y), h6 = bfhi(b.z), h7 = bfhi(b.w);
    h[0] = (short)h0; h[1] = (short)h1; h[2] = (short)h2; h[3] = (short)h3;
    h[4] = (short)h4; h[5] = (short)h5; h[6] = (short)h6; h[7] = (short)h7;
    l[0] = (short)bfhi(a.x - bff(h0)); l[1] = (short)bfhi(a.y - bff(h1));
    l[2] = (short)bfhi(a.z - bff(h2)); l[3] = (short)bfhi(a.w - bff(h3));
    l[4] = (short)bfhi(b.x - bff(h4)); l[5] = (short)bfhi(b.y - bff(h5));
    l[6] = (short)bfhi(b.z - bff(h6)); l[7] = (short)bfhi(b.w - bff(h7));
}
static __device__ __forceinline__ void trunc8(const float4 a, const float4 b,
                                              short8v& h) {
    h[0] = (short)bfhi(a.x); h[1] = (short)bfhi(a.y);
    h[2] = (short)bfhi(a.z); h[3] = (short)bfhi(a.w);
    h[4] = (short)bfhi(b.x); h[5] = (short)bfhi(b.y);
    h[6] = (short)bfhi(b.z); h[7] = (short)bfhi(b.w);
}

// ---------------------------------------------------------------------------
// Weff_tmp[k][z*512+c] = sum_d W[k, h*64+d] * Wlsr[h, d, r]  (z=0:Wq, 1:Wk)
// ---------------------------------------------------------------------------
__global__ __launch_bounds__(256) void eff_weight2(
    const float* __restrict__ Wq, const float* __restrict__ Wq_lsr,
    const float* __restrict__ Wk, const float* __restrict__ Wk_lsr,
    float* __restrict__ Weff_tmp)
{
    const int z = blockIdx.y;
    const float* W    = z ? Wk : Wq;
    const float* Wlsr = z ? Wk_lsr : Wq_lsr;
    const int base = z << 9;
    int idx = blockIdx.x * 256 + threadIdx.x;
    int k = idx >> 9;
    int c = idx & 511;
    int h = c >> 5;
    int r = c & 31;
    const float* wrow = W + (size_t)k * D_MODEL + h * D_HEAD;
    const float* lsr  = Wlsr + (size_t)h * D_HEAD * LSR_RANK + r;
    float acc = 0.f;
    #pragma unroll
    for (int d = 0; d < D_HEAD; ++d)
        acc = fmaf(wrow[d], lsr[d * LSR_RANK], acc);
    Weff_tmp[(size_t)k * 1024 + base + c] = acc;
}

__global__ __launch_bounds__(256) void eff_bias_kernel(
    const float* __restrict__ bq, const float* __restrict__ Wq_lsr,
    const float* __restrict__ bk, const float* __restrict__ Wk_lsr,
    const float* __restrict__ bv, float* __restrict__ bcat)
{
    int c = blockIdx.x * 256 + threadIdx.x;
    if (c < 1024) {
        const float* bias = (c < 512) ? bq : bk;
        const float* lsr  = (c < 512) ? Wq_lsr : Wk_lsr;
        int cc = c & 511;
        int h = cc >> 5, r = cc & 31;
        float acc = 0.f;
        #pragma unroll
        for (int d = 0; d < D_HEAD; ++d)
            acc = fmaf(bias[h * D_HEAD + d],
                       lsr[(size_t)h * D_HEAD * LSR_RANK + d * LSR_RANK + r], acc);
        bcat[c] = acc;
    } else {
        bcat[c] = bv[c - 1024];
    }
}

// ---------------------------------------------------------------------------
// Dual 1024x1024 fp32 transpose: z=0: in0->out0, z=1: in1->out1.
// ---------------------------------------------------------------------------
__global__ __launch_bounds__(256) void transpose2(
    const float* __restrict__ in0, float* __restrict__ out0,
    const float* __restrict__ in1, float* __restrict__ out1)
{
    const float* in  = blockIdx.z ? in1 : in0;
    float* out       = blockIdx.z ? out1 : out0;
    __shared__ float t[64][65];
    const int tid = threadIdx.x;
    const int r0 = blockIdx.y * 64, c0 = blockIdx.x * 64;
    const int tr = tid >> 4, tc = tid & 15;
    #pragma unroll
    for (int i = 0; i < 4; ++i) {
        float4 v = *(const float4*)&in[(size_t)(r0 + tr + i * 16) * 1024 + c0 + tc * 4];
        t[tr + i * 16][tc * 4 + 0] = v.x;
        t[tr + i * 16][tc * 4 + 1] = v.y;
        t[tr + i * 16][tc * 4 + 2] = v.z;
        t[tr + i * 16][tc * 4 + 3] = v.w;
    }
    __syncthreads();
    #pragma unroll
    for (int i = 0; i < 4; ++i) {
        float4 v;
        v.x = t[tc * 4 + 0][tr + i * 16];
        v.y = t[tc * 4 + 1][tr + i * 16];
        v.z = t[tc * 4 + 2][tr + i * 16];
        v.w = t[tc * 4 + 3][tr + i * 16];
        *(float4*)&out[(size_t)(c0 + tr + i * 16) * 1024 + r0 + tc * 4] = v;
    }
}

// ---------------------------------------------------------------------------
// Transpose + bf16-rn: Wo[1024][1024] fp32 -> Wot transposed bf16.
// ---------------------------------------------------------------------------
__global__ __launch_bounds__(256) void tsplit_rn1024(
    const float* __restrict__ in, ushort* __restrict__ out)
{
    __shared__ float t[64][65];
    const int tid = threadIdx.x;
    const int r0 = blockIdx.y * 64, c0 = blockIdx.x * 64;
    const int tr = tid >> 4, tc = tid & 15;
    #pragma unroll
    for (int i = 0; i < 4; ++i) {
        float4 v = *(const float4*)&in[(size_t)(r0 + tr + i * 16) * 1024 + c0 + tc * 4];
        t[tr + i * 16][tc * 4 + 0] = v.x;
        t[tr + i * 16][tc * 4 + 1] = v.y;
        t[tr + i * 16][tc * 4 + 2] = v.z;
        t[tr + i * 16][tc * 4 + 3] = v.w;
    }
    __syncthreads();
    #pragma unroll
    for (int i = 0; i < 4; ++i) {
        short4v hv = {(short)f2bf_rn(t[tc * 4 + 0][tr + i * 16]),
                      (short)f2bf_rn(t[tc * 4 + 1][tr + i * 16]),
                      (short)f2bf_rn(t[tc * 4 + 2][tr + i * 16]),
                      (short)f2bf_rn(t[tc * 4 + 3][tr + i * 16])};
        *(short4v*)&out[(size_t)(c0 + tr + i * 16) * 1024 + r0 + tc * 4] = hv;
    }
}

// ---------------------------------------------------------------------------
// Fused projection GEMM (r22-measured-good) — UNCHANGED.
// ---------------------------------------------------------------------------
__global__ __launch_bounds__(256) void gemm_proj_fused(
    const float* __restrict__ x,
    const float* __restrict__ Wcat_t,
    const float* __restrict__ bcat,
    float* __restrict__ Yqk,
    short* __restrict__ Kth, short* __restrict__ Ktl,
    short* __restrict__ Vbf)
{
    __shared__ __align__(16) short Ah[128 * 40], Al[128 * 40];
    __shared__ __align__(16) short Bh[128 * 40], Bl[128 * 40];

    const int tid = threadIdx.x;
    const int bx = blockIdx.x;
    const int m0 = blockIdx.y * 128, n0 = bx * 128;
    const bool vhalf = (bx >= 8);
    const int wid = tid >> 6, wr = wid >> 1, wc = wid & 1;
    const int lane = tid & 63, fr = lane & 15, fq = lane >> 4;
    const int srow = tid >> 1;
    const int skq  = (tid & 1) << 4;

    f32x4 acc[4][4];
    #pragma unroll
    for (int i = 0; i < 4; ++i)
        #pragma unroll
        for (int j = 0; j < 4; ++j)
            acc[i][j] = (f32x4){0.f, 0.f, 0.f, 0.f};

    const float* Ag = x + (size_t)(m0 + srow) * 1024 + skq;
    const float* Bg = Wcat_t + (size_t)(n0 + srow) * 1024 + skq;
    short* pAh = &Ah[srow * 40 + skq];
    short* pAl = &Al[srow * 40 + skq];
    short* pBh = &Bh[srow * 40 + skq];
    short* pBl = &Bl[srow * 40 + skq];

    for (int k0 = 0; k0 < 1024; k0 += 32) {
        float4 a0 = *(const float4*)(Ag + k0);
        float4 a1 = *(const float4*)(Ag + k0 + 4);
        float4 a2 = *(const float4*)(Ag + k0 + 8);
        float4 a3 = *(const float4*)(Ag + k0 + 12);
        float4 b0 = *(const float4*)(Bg + k0);
        float4 b1 = *(const float4*)(Bg + k0 + 4);
        float4 b2 = *(const float4*)(Bg + k0 + 8);
        float4 b3 = *(const float4*)(Bg + k0 + 12);
        if (vhalf) {
            short8v h;
            trunc8(a0, a1, h); *(short8v*)pAh = h;
            trunc8(a2, a3, h); *(short8v*)(pAh + 8) = h;
            trunc8(b0, b1, h); *(short8v*)pBh = h;
            trunc8(b2, b3, h); *(short8v*)(pBh + 8) = h;
        } else {
            short8v h, l;
            split8(a0, a1, h, l);
            *(short8v*)pAh = h;  *(short8v*)pAl = l;
            split8(a2, a3, h, l);
            *(short8v*)(pAh + 8) = h;  *(short8v*)(pAl + 8) = l;
            split8(b0, b1, h, l);
            *(short8v*)pBh = h;  *(short8v*)pBl = l;
            split8(b2, b3, h, l);
            *(short8v*)(pBh + 8) = h;  *(short8v*)(pBl + 8) = l;
        }
        __syncthreads();

        short8v afh[4], bfh[4];
        #pragma unroll
        for (int fi = 0; fi < 4; ++fi)
            afh[fi] = *(const short8v*)&Ah[(wr * 64 + fi * 16 + fr) * 40 + fq * 8];
        #pragma unroll
        for (int bj = 0; bj < 4; ++bj)
            bfh[bj] = *(const short8v*)&Bh[(wc * 64 + bj * 16 + fr) * 40 + fq * 8];

        if (vhalf) {
            #pragma unroll
            for (int fi = 0; fi < 4; ++fi)
                #pragma unroll
                for (int bj = 0; bj < 4; ++bj)
                    acc[fi][bj] = __builtin_amdgcn_mfma_f32_16x16x32_bf16(
                        afh[fi], bfh[bj], acc[fi][bj], 0, 0, 0);
        } else {
            short8v afl[4], bfl[4];
            #pragma unroll
            for (int fi = 0; fi < 4; ++fi)
                afl[fi] = *(const short8v*)&Al[(wr * 64 + fi * 16 + fr) * 40 + fq * 8];
            #pragma unroll
            for (int bj = 0; bj < 4; ++bj)
                bfl[bj] = *(const short8v*)&Bl[(wc * 64 + bj * 16 + fr) * 40 + fq * 8];
            #pragma unroll
            for (int fi = 0; fi < 4; ++fi) {
                #pragma unroll
                for (int bj = 0; bj < 4; ++bj) {
                    acc[fi][bj] = __builtin_amdgcn_mfma_f32_16x16x32_bf16(
                        afh[fi], bfh[bj], acc[fi][bj], 0, 0, 0);
                    acc[fi][bj] = __builtin_amdgcn_mfma_f32_16x16x32_bf16(
                        afh[fi], bfl[bj], acc[fi][bj], 0, 0, 0);
                    acc[fi][bj] = __builtin_amdgcn_mfma_f32_16x16x32_bf16(
                        afl[fi], bfh[bj], acc[fi][bj], 0, 0, 0);
                }
            }
        }
        __syncthreads();
    }

    const int b = m0 >> 11;
    #pragma unroll
    for (int fi = 0; fi < 4; ++fi) {
        #pragma unroll
        for (int bj = 0; bj < 4; ++bj) {
            const int r = m0 + wr * 64 + fi * 16 + fq * 4;
            const int gcol = n0 + wc * 64 + bj * 16 + fr;
            const float bv_ = bcat[gcol];
            if (bx < 4) {
                #pragma unroll
                for (int j = 0; j < 4; ++j)
                    Yqk[(size_t)(r + j) * 1024 + gcol] = acc[fi][bj][j] + bv_;
            } else if (bx < 8) {
                const int kc = gcol - 512;
                const int h = kc >> 5, rr = kc & 31;
                short* oh = Kth + (((size_t)(b * 16 + h) * 2048) + (r & 2047)) * 32 + rr;
                short* ol = Ktl + (((size_t)(b * 16 + h) * 2048) + (r & 2047)) * 32 + rr;
                #pragma unroll
                for (int j = 0; j < 4; ++j) {
                    const float v = acc[fi][bj][j] + bv_;
                    const ushort vh = bfhi(v);
                    oh[j * 32] = (short)vh;
                    ol[j * 32] = (short)bfhi(v - bff(vh));
                }
            } else {
                const int vc = gcol - 1024;
                const int h = vc >> 6, d = vc & 63;
                short4v o = {(short)f2bf_rn(acc[fi][bj][0] + bv_),
                             (short)f2bf_rn(acc[fi][bj][1] + bv_),
                             (short)f2bf_rn(acc[fi][bj][2] + bv_),
                             (short)f2bf_rn(acc[fi][bj][3] + bv_)};
                *(short4v*)&Vbf[((size_t)(b * 16 + h) * 64 + d) * 2048 + (r & 2047)] = o;
            }
        }
    }
}

// ---------------------------------------------------------------------------
// Out-proj GEMM, 1-term bf16 (r19-validated) — UNCHANGED.
// ---------------------------------------------------------------------------
__global__ __launch_bounds__(256) void gemm_out_bf(
    const ushort* __restrict__ Obf,
    const ushort* __restrict__ Wot,
    const float* __restrict__ bo,
    float* __restrict__ out)
{
    __shared__ __align__(16) short Ah[128 * 40];
    __shared__ __align__(16) short Bh[128 * 40];

    const int tid = threadIdx.x;
    const int m0 = blockIdx.y * 128, n0 = blockIdx.x * 128;
    const int wid = tid >> 6, wr = wid >> 1, wc = wid & 1;
    const int lane = tid & 63, fr = lane & 15, fq = lane >> 4;
    const int srow = tid >> 1;
    const int skq  = (tid & 1) << 4;

    f32x4 acc[4][4];
    #pragma unroll
    for (int i = 0; i < 4; ++i)
        #pragma unroll
        for (int j = 0; j < 4; ++j)
            acc[i][j] = (f32x4){0.f, 0.f, 0.f, 0.f};

    const ushort* AgH = Obf + (size_t)(m0 + srow) * 1024 + skq;
    const ushort* BgH = Wot + (size_t)(n0 + srow) * 1024 + skq;
    short* pAh = &Ah[srow * 40 + skq];
    short* pBh = &Bh[srow * 40 + skq];

    for (int k0 = 0; k0 < 1024; k0 += 32) {
        *(short8v*)pAh       = *(const short8v*)(AgH + k0);
        *(short8v*)(pAh + 8) = *(const short8v*)(AgH + k0 + 8);
        *(short8v*)pBh       = *(const short8v*)(BgH + k0);
        *(short8v*)(pBh + 8) = *(const short8v*)(BgH + k0 + 8);
        __syncthreads();

        short8v afh[4], bfh[4];
        #pragma unroll
        for (int fi = 0; fi < 4; ++fi)
            afh[fi] = *(const short8v*)&Ah[(wr * 64 + fi * 16 + fr) * 40 + fq * 8];
        #pragma unroll
        for (int bj = 0; bj < 4; ++bj)
            bfh[bj] = *(const short8v*)&Bh[(wc * 64 + bj * 16 + fr) * 40 + fq * 8];
        #pragma unroll
        for (int fi = 0; fi < 4; ++fi)
            #pragma unroll
            for (int bj = 0; bj < 4; ++bj)
                acc[fi][bj] = __builtin_amdgcn_mfma_f32_16x16x32_bf16(
                    afh[fi], bfh[bj], acc[fi][bj], 0, 0, 0);
        __syncthreads();
    }

    #pragma unroll
    for (int fi = 0; fi < 4; ++fi) {
        #pragma unroll
        for (int bj = 0; bj < 4; ++bj) {
            const int r = m0 + wr * 64 + fi * 16 + fq * 4;
            const int c = n0 + wc * 64 + bj * 16 + fr;
            const float bv_ = bo[c];
            #pragma unroll
            for (int j = 0; j < 4; ++j)
                out[(size_t)(r + j) * 1024 + c] = acc[fi][bj][j] + bv_;
        }
    }
}

// ---------------------------------------------------------------------------
// MFMA flash attention v12 = dual-Q (r25/r28-proven) + cross-iteration
// K-PREFETCH. The K fragments for iteration jt+2 are loaded BEFORE the
// compute of jt and consumed only next iteration — a data-dependence change
// (not a scheduling hint): the compiler must keep them live, so their waits
// land a full iteration later. K-only (+32 VGPR -> ~124) stays under the
// 128-VGPR/4-waves-per-SIMD tier, preserving dual-Q's residency.
// jt+2 clamped to qtB (redundant in-bounds load on the last iteration).
// ---------------------------------------------------------------------------
#define P_LD  68
#define MASKVAL (-1e30f)

__global__ __launch_bounds__(512) void flash_mfma(
    const float* __restrict__ Yqk,
    const short* __restrict__ Kth, const short* __restrict__ Ktl,
    const short* __restrict__ Vbf,
    ushort* __restrict__ Obf)
{
    const float scale = 0.1767766952966369f;  // 1/sqrt(32)
    const int L = blockIdx.x;
    const int bh = L & 31;
    const int qp = 15 - (L >> 5);              // LPT: big pairs first
    const int qtA = 2 * qp, qtB = 2 * qp + 1;
    const int b = bh >> 4, h = bh & 15;
    const int tid = threadIdx.x;
    const int w = tid >> 6;
    const int g = w & 3;
    const int p = w >> 2;
    const int lane = tid & 63;
    const int fr = lane & 15, fq = lane >> 4;

    __shared__ __align__(16) short Pall[8][16 * P_LD];        // 17408 B
    __shared__ __align__(16) char exraw[4 * 64 * 80];         // 20480 B
    short* Pw = &Pall[w][0];

    short8v aqhA, aqlA, aqhB, aqlB;
    {
        const float* qpA = Yqk + (size_t)(b * SEQ + qtA * 64 + g * 16 + fr) * 1024
                           + h * 32 + fq * 8;
        split8(*(const float4*)qpA, *(const float4*)(qpA + 4), aqhA, aqlA);
        const float* qpB = Yqk + (size_t)(b * SEQ + qtB * 64 + g * 16 + fr) * 1024
                           + h * 32 + fq * 8;
        split8(*(const float4*)qpB, *(const float4*)(qpB + 4), aqhB, aqlB);
    }

    f32x4 accA0 = {0,0,0,0}, accA1 = {0,0,0,0}, accA2 = {0,0,0,0}, accA3 = {0,0,0,0};
    f32x4 accB0 = {0,0,0,0}, accB1 = {0,0,0,0}, accB2 = {0,0,0,0}, accB3 = {0,0,0,0};
    float mA[4], lA[4], mB[4], lB[4];
    #pragma unroll
    for (int r = 0; r < 4; ++r) {
        mA[r] = MASKVAL; lA[r] = 0.f;
        mB[r] = MASKVAL; lB[r] = 0.f;
    }

    const short* kb_h = Kth + (size_t)bh * 2048 * 32;
    const short* kb_l = Ktl + (size_t)bh * 2048 * 32;
    const short* vb   = Vbf + (size_t)bh * 64 * 2048;
    const int kidx = fr * 32 + fq * 8;
    const int vrow = fr * 2048 + fq * 8;

    // ---- prologue: load K fragments for the first iteration (jt = p) ----
    short8v kh0, kh1, kh2, kh3, kl0, kl1, kl2, kl3;
    {
        const short* kp_h = kb_h + (size_t)p * 64 * 32;
        const short* kp_l = kb_l + (size_t)p * 64 * 32;
        kh0 = *(const short8v*)&kp_h[kidx];
        kh1 = *(const short8v*)&kp_h[kidx + 512];
        kh2 = *(const short8v*)&kp_h[kidx + 1024];
        kh3 = *(const short8v*)&kp_h[kidx + 1536];
        kl0 = *(const short8v*)&kp_l[kidx];
        kl1 = *(const short8v*)&kp_l[kidx + 512];
        kl2 = *(const short8v*)&kp_l[kidx + 1024];
        kl3 = *(const short8v*)&kp_l[kidx + 1536];
    }

    for (int jt = p; jt <= qtB; jt += 2) {
        // ---- issue NEXT iteration's K loads (consumed next iter) ----
        const int jtn = (jt + 2 <= qtB) ? (jt + 2) : jt;
        const short* kpn_h = kb_h + (size_t)jtn * 64 * 32;
        const short* kpn_l = kb_l + (size_t)jtn * 64 * 32;
        short8v nkh0 = *(const short8v*)&kpn_h[kidx];
        short8v nkh1 = *(const short8v*)&kpn_h[kidx + 512];
        short8v nkh2 = *(const short8v*)&kpn_h[kidx + 1024];
        short8v nkh3 = *(const short8v*)&kpn_h[kidx + 1536];
        short8v nkl0 = *(const short8v*)&kpn_l[kidx];
        short8v nkl1 = *(const short8v*)&kpn_l[kidx + 512];
        short8v nkl2 = *(const short8v*)&kpn_l[kidx + 1024];
        short8v nkl3 = *(const short8v*)&kpn_l[kidx + 1536];

        // ---- V loads for the CURRENT iteration ----
        const short* vp = vb + vrow + jt * 64;
        short8v v00 = *(const short8v*)&vp[0];
        short8v v01 = *(const short8v*)&vp[32];
        short8v v10 = *(const short8v*)&vp[16 * 2048];
        short8v v11 = *(const short8v*)&vp[16 * 2048 + 32];
        short8v v20 = *(const short8v*)&vp[32 * 2048];
        short8v v21 = *(const short8v*)&vp[32 * 2048 + 32];
        short8v v30 = *(const short8v*)&vp[48 * 2048];
        short8v v31 = *(const short8v*)&vp[48 * 2048 + 32];

        // ================= tile A (skip wave-uniformly if past causal) ====
        if (jt <= qtA) {
            f32x4 s0 = {0,0,0,0}, s1 = {0,0,0,0}, s2 = {0,0,0,0}, s3 = {0,0,0,0};
            s0 = __builtin_amdgcn_mfma_f32_16x16x32_bf16(aqhA, kh0, s0, 0, 0, 0);
            s0 = __builtin_amdgcn_mfma_f32_16x16x32_bf16(aqhA, kl0, s0, 0, 0, 0);
            s0 = __builtin_amdgcn_mfma_f32_16x16x32_bf16(aqlA, kh0, s0, 0, 0, 0);
            s1 = __builtin_amdgcn_mfma_f32_16x16x32_bf16(aqhA, kh1, s1, 0, 0, 0);
            s1 = __builtin_amdgcn_mfma_f32_16x16x32_bf16(aqhA, kl1, s1, 0, 0, 0);
            s1 = __builtin_amdgcn_mfma_f32_16x16x32_bf16(aqlA, kh1, s1, 0, 0, 0);
            s2 = __builtin_amdgcn_mfma_f32_16x16x32_bf16(aqhA, kh2, s2, 0, 0, 0);
            s2 = __builtin_amdgcn_mfma_f32_16x16x32_bf16(aqhA, kl2, s2, 0, 0, 0);
            s2 = __builtin_amdgcn_mfma_f32_16x16x32_bf16(aqlA, kh2, s2, 0, 0, 0);
            s3 = __builtin_amdgcn_mfma_f32_16x16x32_bf16(aqhA, kh3, s3, 0, 0, 0);
            s3 = __builtin_amdgcn_mfma_f32_16x16x32_bf16(aqhA, kl3, s3, 0, 0, 0);
            s3 = __builtin_amdgcn_mfma_f32_16x16x32_bf16(aqlA, kh3, s3, 0, 0, 0);

            s0 *= scale; s1 *= scale; s2 *= scale; s3 *= scale;

            if (jt == qtA) {
                #pragma unroll
                for (int r = 0; r < 4; ++r) {
                    const int q_l = g * 16 + fq * 4 + r;
                    s0[r] = (fr      <= q_l) ? s0[r] : MASKVAL;
                    s1[r] = (16 + fr <= q_l) ? s1[r] : MASKVAL;
                    s2[r] = (32 + fr <= q_l) ? s2[r] : MASKVAL;
                    s3[r] = (48 + fr <= q_l) ? s3[r] : MASKVAL;
                }
            }

            float al[4];
            #pragma unroll
            for (int r = 0; r < 4; ++r) {
                float mt = fmaxf(fmaxf(s0[r], s1[r]), fmaxf(s2[r], s3[r]));
                mt = fmaxf(mt, __shfl_xor(mt, 1));
                mt = fmaxf(mt, __shfl_xor(mt, 2));
                mt = fmaxf(mt, __shfl_xor(mt, 4));
                mt = fmaxf(mt, __shfl_xor(mt, 8));
                const float mnew = fmaxf(mA[r], mt);
                al[r] = __expf(mA[r] - mnew);
                mA[r] = mnew;
                s0[r] = __expf(s0[r] - mnew);
                s1[r] = __expf(s1[r] - mnew);
                s2[r] = __expf(s2[r] - mnew);
                s3[r] = __expf(s3[r] - mnew);
                float ps = s0[r] + s1[r] + s2[r] + s3[r];
                ps += __shfl_xor(ps, 1);
                ps += __shfl_xor(ps, 2);
                ps += __shfl_xor(ps, 4);
                ps += __shfl_xor(ps, 8);
                lA[r] = lA[r] * al[r] + ps;
            }

            #pragma unroll
            for (int r = 0; r < 4; ++r) {
                const int prow = fq * 4 + r;
                Pw[prow * P_LD +      fr] = (short)f2bf_rn(s0[r]);
                Pw[prow * P_LD + 16 + fr] = (short)f2bf_rn(s1[r]);
                Pw[prow * P_LD + 32 + fr] = (short)f2bf_rn(s2[r]);
                Pw[prow * P_LD + 48 + fr] = (short)f2bf_rn(s3[r]);
            }
            #pragma unroll
            for (int r = 0; r < 4; ++r) {
                accA0[r] *= al[r]; accA1[r] *= al[r];
                accA2[r] *= al[r]; accA3[r] *= al[r];
            }
            short8v pa0 = *(const short8v*)&Pw[fr * P_LD + fq * 8];
            short8v pa1 = *(const short8v*)&Pw[fr * P_LD + 32 + fq * 8];

            accA0 = __builtin_amdgcn_mfma_f32_16x16x32_bf16(pa0, v00, accA0, 0, 0, 0);
            accA0 = __builtin_amdgcn_mfma_f32_16x16x32_bf16(pa1, v01, accA0, 0, 0, 0);
            accA1 = __builtin_amdgcn_mfma_f32_16x16x32_bf16(pa0, v10, accA1, 0, 0, 0);
            accA1 = __builtin_amdgcn_mfma_f32_16x16x32_bf16(pa1, v11, accA1, 0, 0, 0);
            accA2 = __builtin_amdgcn_mfma_f32_16x16x32_bf16(pa0, v20, accA2, 0, 0, 0);
            accA2 = __builtin_amdgcn_mfma_f32_16x16x32_bf16(pa1, v21, accA2, 0, 0, 0);
            accA3 = __builtin_amdgcn_mfma_f32_16x16x32_bf16(pa0, v30, accA3, 0, 0, 0);
            accA3 = __builtin_amdgcn_mfma_f32_16x16x32_bf16(pa1, v31, accA3, 0, 0, 0);
        }

        // ================= tile B (always active: jt <= qtB by loop) ======
        {
            f32x4 s0 = {0,0,0,0}, s1 = {0,0,0,0}, s2 = {0,0,0,0}, s3 = {0,0,0,0};
            s0 = __builtin_amdgcn_mfma_f32_16x16x32_bf16(aqhB, kh0, s0, 0, 0, 0);
            s0 = __builtin_amdgcn_mfma_f32_16x16x32_bf16(aqhB, kl0, s0, 0, 0, 0);
            s0 = __builtin_amdgcn_mfma_f32_16x16x32_bf16(aqlB, kh0, s0, 0, 0, 0);
            s1 = __builtin_amdgcn_mfma_f32_16x16x32_bf16(aqhB, kh1, s1, 0, 0, 0);
            s1 = __builtin_amdgcn_mfma_f32_16x16x32_bf16(aqhB, kl1, s1, 0, 0, 0);
            s1 = __builtin_amdgcn_mfma_f32_16x16x32_bf16(aqlB, kh1, s1, 0, 0, 0);
            s2 = __builtin_amdgcn_mfma_f32_16x16x32_bf16(aqhB, kh2, s2, 0, 0, 0);
            s2 = __builtin_amdgcn_mfma_f32_16x16x32_bf16(aqhB, kl2, s2, 0, 0, 0);
            s2 = __builtin_amdgcn_mfma_f32_16x16x32_bf16(aqlB, kh2, s2, 0, 0, 0);
            s3 = __builtin_amdgcn_mfma_f32_16x16x32_bf16(aqhB, kh3, s3, 0, 0, 0);
            s3 = __builtin_amdgcn_mfma_f32_16x16x32_bf16(aqhB, kl3, s3, 0, 0, 0);
            s3 = __builtin_amdgcn_mfma_f32_16x16x32_bf16(aqlB, kh3, s3, 0, 0, 0);

            s0 *= scale; s1 *= scale; s2 *= scale; s3 *= scale;

            if (jt == qtB) {
                #pragma unroll
                for (int r = 0; r < 4; ++r) {
                    const int q_l = g * 16 + fq * 4 + r;
                    s0[r] = (fr      <= q_l) ? s0[r] : MASKVAL;
                    s1[r] = (16 + fr <= q_l) ? s1[r] : MASKVAL;
                    s2[r] = (32 + fr <= q_l) ? s2[r] : MASKVAL;
                    s3[r] = (48 + fr <= q_l) ? s3[r] : MASKVAL;
                }
            }

            float al[4];
            #pragma unroll
            for (int r = 0; r < 4; ++r) {
                float mt = fmaxf(fmaxf(s0[r], s1[r]), fmaxf(s2[r], s3[r]));
                mt = fmaxf(mt, __shfl_xor(mt, 1));
                mt = fmaxf(mt, __shfl_xor(mt, 2));
                mt = fmaxf(mt, __shfl_xor(mt, 4));
                mt = fmaxf(mt, __shfl_xor(mt, 8));
                const float mnew = fmaxf(mB[r], mt);
                al[r] = __expf(mB[r] - mnew);
                mB[r] = mnew;
                s0[r] = __expf(s0[r] - mnew);
                s1[r] = __expf(s1[r] - mnew);
                s2[r] = __expf(s2[r] - mnew);
                s3[r] = __expf(s3[r] - mnew);
                float ps = s0[r] + s1[r] + s2[r] + s3[r];
                ps += __shfl_xor(ps, 1);
                ps += __shfl_xor(ps, 2);
                ps += __shfl_xor(ps, 4);
                ps += __shfl_xor(ps, 8);
                lB[r] = lB[r] * al[r] + ps;
            }

            #pragma unroll
            for (int r = 0; r < 4; ++r) {
                const int prow = fq * 4 + r;
                Pw[prow * P_LD +      fr] = (short)f2bf_rn(s0[r]);
                Pw[prow * P_LD + 16 + fr] = (short)f2bf_rn(s1[r]);
                Pw[prow * P_LD + 32 + fr] = (short)f2bf_rn(s2[r]);
                Pw[prow * P_LD + 48 + fr] = (short)f2bf_rn(s3[r]);
            }
            #pragma unroll
            for (int r = 0; r < 4; ++r) {
                accB0[r] *= al[r]; accB1[r] *= al[r];
                accB2[r] *= al[r]; accB3[r] *= al[r];
            }
            short8v pa0 = *(const short8v*)&Pw[fr * P_LD + fq * 8];
            short8v pa1 = *(const short8v*)&Pw[fr * P_LD + 32 + fq * 8];

            accB0 = __builtin_amdgcn_mfma_f32_16x16x32_bf16(pa0, v00, accB0, 0, 0, 0);
            accB0 = __builtin_amdgcn_mfma_f32_16x16x32_bf16(pa1, v01, accB0, 0, 0, 0);
            accB1 = __builtin_amdgcn_mfma_f32_16x16x32_bf16(pa0, v10, accB1, 0, 0, 0);
            accB1 = __builtin_amdgcn_mfma_f32_16x16x32_bf16(pa1, v11, accB1, 0, 0, 0);
            accB2 = __builtin_amdgcn_mfma_f32_16x16x32_bf16(pa0, v20, accB2, 0, 0, 0);
            accB2 = __builtin_amdgcn_mfma_f32_16x16x32_bf16(pa1, v21, accB2, 0, 0, 0);
            accB3 = __builtin_amdgcn_mfma_f32_16x16x32_bf16(pa0, v30, accB3, 0, 0, 0);
            accB3 = __builtin_amdgcn_mfma_f32_16x16x32_bf16(pa1, v31, accB3, 0, 0, 0);
        }

        // ---- rotate prefetched K into current ----
        kh0 = nkh0; kh1 = nkh1; kh2 = nkh2; kh3 = nkh3;
        kl0 = nkl0; kl1 = nkl1; kl2 = nkl2; kl3 = nkl3;
    }

    // ---- epilogue: two merge rounds through the shared ex buffer ----
    char* e = exraw + (size_t)(((g << 6) + lane) * 80);

    // round 1: tile A
    if (p == 1) {
        short8v a01, a23;
        a01[0] = (short)f2bf_rn(accA0[0]); a01[1] = (short)f2bf_rn(accA0[1]);
        a01[2] = (short)f2bf_rn(accA0[2]); a01[3] = (short)f2bf_rn(accA0[3]);
        a01[4] = (short)f2bf_rn(accA1[0]); a01[5] = (short)f2bf_rn(accA1[1]);
        a01[6] = (short)f2bf_rn(accA1[2]); a01[7] = (short)f2bf_rn(accA1[3]);
        a23[0] = (short)f2bf_rn(accA2[0]); a23[1] = (short)f2bf_rn(accA2[1]);
        a23[2] = (short)f2bf_rn(accA2[2]); a23[3] = (short)f2bf_rn(accA2[3]);
        a23[4] = (short)f2bf_rn(accA3[0]); a23[5] = (short)f2bf_rn(accA3[1]);
        a23[6] = (short)f2bf_rn(accA3[2]); a23[7] = (short)f2bf_rn(accA3[3]);
        *(short8v*)(e)      = a01;
        *(short8v*)(e + 16) = a23;
        *(f32x4*)(e + 32) = (f32x4){mA[0], mA[1], mA[2], mA[3]};
        *(f32x4*)(e + 48) = (f32x4){lA[0], lA[1], lA[2], lA[3]};
    }
    __syncthreads();
    if (p == 0) {
        short8v a01 = *(const short8v*)(e);
        short8v a23 = *(const short8v*)(e + 16);
        f32x4 m1 = *(const f32x4*)(e + 32);
        f32x4 l1 = *(const f32x4*)(e + 48);
        #pragma unroll
        for (int r = 0; r < 4; ++r) {
            const float mm = fmaxf(mA[r], m1[r]);
            const float a0 = __expf(mA[r] - mm);
            const float a1 = __expf(m1[r] - mm);
            const float inv = 1.f / (lA[r] * a0 + l1[r] * a1);
            const float b0 = bff((ushort)a01[r]);
            const float b1 = bff((ushort)a01[4 + r]);
            const float b2 = bff((ushort)a23[r]);
            const float b3 = bff((ushort)a23[4 + r]);
            const int trow = qtA * 64 + g * 16 + fq * 4 + r;
            ushort* op = Obf + (size_t)(b * SEQ + trow) * 1024 + h * 64;
            op[     fr] = f2bf_rn((accA0[r] * a0 + b0 * a1) * inv);
            op[16 + fr] = f2bf_rn((accA1[r] * a0 + b1 * a1) * inv);
            op[32 + fr] = f2bf_rn((accA2[r] * a0 + b2 * a1) * inv);
            op[48 + fr] = f2bf_rn((accA3[r] * a0 + b3 * a1) * inv);
        }
    }
    __syncthreads();

    // round 2: tile B
    if (p == 1) {
        short8v a01, a23;
        a01[0] = (short)f2bf_rn(accB0[0]); a01[1] = (short)f2bf_rn(accB0[1]);
        a01[2] = (short)f2bf_rn(accB0[2]); a01[3] = (short)f2bf_rn(accB0[3]);
        a01[4] = (short)f2bf_rn(accB1[0]); a01[5] = (short)f2bf_rn(accB1[1]);
        a01[6] = (short)f2bf_rn(accB1[2]); a01[7] = (short)f2bf_rn(accB1[3]);
        a23[0] = (short)f2bf_rn(accB2[0]); a23[1] = (short)f2bf_rn(accB2[1]);
        a23[2] = (short)f2bf_rn(accB2[2]); a23[3] = (short)f2bf_rn(accB2[3]);
        a23[4] = (short)f2bf_rn(accB3[0]); a23[5] = (short)f2bf_rn(accB3[1]);
        a23[6] = (short)f2bf_rn(accB3[2]); a23[7] = (short)f2bf_rn(accB3[3]);
        *(short8v*)(e)      = a01;
        *(short8v*)(e + 16) = a23;
        *(f32x4*)(e + 32) = (f32x4){mB[0], mB[1], mB[2], mB[3]};
        *(f32x4*)(e + 48) = (f32x4){lB[0], lB[1], lB[2], lB[3]};
    }
    __syncthreads();
    if (p == 0) {
        short8v a01 = *(const short8v*)(e);
        short8v a23 = *(const short8v*)(e + 16);
        f32x4 m1 = *(const f32x4*)(e + 32);
        f32x4 l1 = *(const f32x4*)(e + 48);
        #pragma unroll
        for (int r = 0; r < 4; ++r) {
            const float mm = fmaxf(mB[r], m1[r]);
            const float a0 = __expf(mB[r] - mm);
            const float a1 = __expf(m1[r] - mm);
            const float inv = 1.f / (lB[r] * a0 + l1[r] * a1);
            const float b0 = bff((ushort)a01[r]);
            const float b1 = bff((ushort)a01[4 + r]);
            const float b2 = bff((ushort)a23[r]);
            const float b3 = bff((ushort)a23[4 + r]);
            const int trow = qtB * 64 + g * 16 + fq * 4 + r;
            ushort* op = Obf + (size_t)(b * SEQ + trow) * 1024 + h * 64;
            op[     fr] = f2bf_rn((accB0[r] * a0 + b0 * a1) * inv);
            op[16 + fr] = f2bf_rn((accB1[r] * a0 + b1 * a1) * inv);
            op[32 + fr] = f2bf_rn((accB2[r] * a0 + b2 * a1) * inv);
            op[48 + fr] = f2bf_rn((accB3[r] * a0 + b3 * a1) * inv);
        }
    }
}

// ---------------------------------------------------------------------------
extern "C" void kernel_launch(void* const* d_in, const int* in_sizes, int n_in,
                              void* d_out, int out_size, void* d_ws, size_t ws_size,
                              hipStream_t stream)
{
    const float* x      = (const float*)d_in[0];
    const float* Wq     = (const float*)d_in[1];
    const float* bq     = (const float*)d_in[2];
    const float* Wk     = (const float*)d_in[3];
    const float* bk     = (const float*)d_in[4];
    const float* Wv     = (const float*)d_in[5];
    const float* bv     = (const float*)d_in[6];
    const float* Wo     = (const float*)d_in[7];
    const float* bo     = (const float*)d_in[8];
    const float* Wq_lsr = (const float*)d_in[9];
    const float* Wk_lsr = (const float*)d_in[10];
    float* out = (float*)d_out;

    float* ws     = (float*)d_ws;
    float* Wcat_t = ws;
    float* bcat   = Wcat_t + (size_t)2048 * 1024;
    float* Yqk    = bcat + 2048;
    float* Weff_tmp = Yqk;
    short* Kth    = (short*)(Yqk + (size_t)M_TOT * 1024);
    short* Ktl    = Kth + (size_t)32 * 2048 * 32;
    short* Vbf    = Ktl + (size_t)32 * 2048 * 32;
    ushort* Obf   = (ushort*)(Vbf + (size_t)32 * 64 * 2048);
    ushort* Wot   = (ushort*)Wcat_t;

    eff_weight2<<<dim3(2048, 2), 256, 0, stream>>>(Wq, Wq_lsr, Wk, Wk_lsr, Weff_tmp);
    eff_bias_kernel<<<8, 256, 0, stream>>>(bq, Wq_lsr, bk, Wk_lsr, bv, bcat);

    transpose2<<<dim3(16, 16, 2), 256, 0, stream>>>(
        Weff_tmp, Wcat_t, Wv, Wcat_t + (size_t)1024 * 1024);

    gemm_proj_fused<<<dim3(16, 32), 256, 0, stream>>>(
        x, Wcat_t, bcat, Yqk, Kth, Ktl, Vbf);

    tsplit_rn1024<<<dim3(16, 16), 256, 0, stream>>>(Wo, Wot);

    flash_mfma<<<512, 512, 0, stream>>>(Yqk, Kth, Ktl, Vbf, Obf);

    gemm_out_bf<<<dim3(8, 32), 256, 0, stream>>>(Obf, Wot, bo, out);
}